// Round 9
// baseline (456.003 us; speedup 1.0000x reference)
//
#include <hip/hip_runtime.h>
#include <hip/hip_bf16.h>

typedef __attribute__((ext_vector_type(8))) short v8s;   // 8 x bf16 (as i16)
typedef __attribute__((ext_vector_type(4))) float v4f;
typedef unsigned short u16;

static constexpr int TT = 2048;        // tokens
static constexpr int HD = 2048;        // hidden
static constexpr int FD = 8192;        // ffn dim
static constexpr int NE = 8;           // experts
static constexpr int NR = 16;          // lora rank
static constexpr int NXE = 2*FD;       // 16384: merged [Wg | Wu] cols
static constexpr int CU_OFF = FD;      // up offset inside CGU row
static constexpr int KXD = FD + 512;   // 8704 = 136*64 ext K for down GEMM (34*64*4)

// ---------- helpers ----------
__device__ __forceinline__ u16 f2b(float f) {            // fp32 -> bf16 RNE
  union { float f; unsigned u; } v; v.f = f;
  unsigned r = v.u + 0x7FFFu + ((v.u >> 16) & 1u);
  return (u16)(r >> 16);
}
__device__ __forceinline__ float b2f(u16 h) {
  union { unsigned u; float f; } v; v.u = ((unsigned)h) << 16;
  return v.f;
}
__device__ __forceinline__ v8s pack8(v4f a, v4f b) {
  v8s r;
  r[0]=(short)f2b(a.x); r[1]=(short)f2b(a.y); r[2]=(short)f2b(a.z); r[3]=(short)f2b(a.w);
  r[4]=(short)f2b(b.x); r[5]=(short)f2b(b.y); r[6]=(short)f2b(b.z); r[7]=(short)f2b(b.w);
  return r;
}
__device__ __forceinline__ void gload_lds16(const void* g, void* l) {
  __builtin_amdgcn_global_load_lds(
      (const __attribute__((address_space(1))) unsigned int*)g,
      (__attribute__((address_space(3))) unsigned int*)l, 16, 0, 0);
}
__device__ __forceinline__ void barrier_pin() {
  __builtin_amdgcn_s_barrier();
  __builtin_amdgcn_sched_barrier(0);
}
__device__ __forceinline__ void vm_wait4() { asm volatile("s_waitcnt vmcnt(4)" ::: "memory"); }
__device__ __forceinline__ void vm_wait0() { asm volatile("s_waitcnt vmcnt(0)" ::: "memory"); }

template<int Q>
__device__ __forceinline__ void mmq(v4f (&acc)[8][4], const v8s (&af)[2][2], const v8s (&bf)[4][2]) {
  __builtin_amdgcn_s_setprio(1);
  #pragma unroll
  for (int m2 = 0; m2 < 2; ++m2)
    #pragma unroll
    for (int nf = 0; nf < 4; ++nf) {
      acc[Q*2+m2][nf] = __builtin_amdgcn_mfma_f32_16x16x32_bf16(af[m2][0], bf[nf][0], acc[Q*2+m2][nf], 0, 0, 0);
      acc[Q*2+m2][nf] = __builtin_amdgcn_mfma_f32_16x16x32_bf16(af[m2][1], bf[nf][1], acc[Q*2+m2][nf], 0, 0, 0);
    }
  __builtin_amdgcn_s_setprio(0);
}

// ---------- mega prep v2: 16 fp32/thread (4 loads in flight -> MLP) ----------
// block = 4096 elems. ranges:
//  [0,1024) h  [1024,5120) Wg  [5120,9216) Wu  [9216,13312) Wd->Wdx(ld)
//  [13312,13376) Ag  [13376,13440) Au  [13440,13696) Bg  [13696,13952) Bu
//  [13952,14208) Ad  [14208,14464) Bd->Wdx ext  [14464,14592) zero hAx
static constexpr int PREP_BLOCKS = 14592;
__global__ __launch_bounds__(256)
void prep_kernel(const float* __restrict__ h, const float* __restrict__ Wg,
                 const float* __restrict__ Wu, const float* __restrict__ Wd,
                 const float* __restrict__ Ag, const float* __restrict__ Au,
                 const float* __restrict__ Bg, const float* __restrict__ Bu,
                 const float* __restrict__ Ad, const float* __restrict__ Bd,
                 u16* __restrict__ hb, u16* __restrict__ Bgux, u16* __restrict__ Agu,
                 u16* __restrict__ Wdx, u16* __restrict__ Bgb, u16* __restrict__ Bub,
                 u16* __restrict__ Adb, float* __restrict__ hAx) {
  const int b = blockIdx.x, tid = threadIdx.x;
  auto cast16 = [&](const float* s, u16* d, long blk) {
    long i = blk*4096 + (long)tid*16;
    v4f a0 = *(const v4f*)(s+i),    a1 = *(const v4f*)(s+i+4);
    v4f a2 = *(const v4f*)(s+i+8),  a3 = *(const v4f*)(s+i+12);
    *(v8s*)(d+i)   = pack8(a0, a1);
    *(v8s*)(d+i+8) = pack8(a2, a3);
  };
  if (b < 1024) { cast16(h, hb, b); }
  else if (b < 5120)  { cast16(Wg, Bgux, b-1024); }
  else if (b < 9216)  { cast16(Wu, Bgux + (size_t)FD*HD, b-5120); }
  else if (b < 13312) {
    long idx = (long)(b-9216)*4096 + (long)tid*16;   // over [HD][FD]
    long r = idx >> 13; int c = (int)(idx & 8191);
    const float* s = Wd + r*FD + c;
    u16* d = Wdx + r*KXD + c;
    v4f a0 = *(const v4f*)s,     a1 = *(const v4f*)(s+4);
    v4f a2 = *(const v4f*)(s+8), a3 = *(const v4f*)(s+12);
    *(v8s*)d     = pack8(a0, a1);
    *(v8s*)(d+8) = pack8(a2, a3);
  }
  else if (b < 13376) { cast16(Ag, Agu, b-13312); }
  else if (b < 13440) { cast16(Au, Agu + (size_t)128*HD, b-13376); }
  else if (b < 13696) { cast16(Bg, Bgb, b-13440); }
  else if (b < 13952) { cast16(Bu, Bub, b-13696); }
  else if (b < 14208) { cast16(Ad, Adb, b-13952); }
  else if (b < 14464) {
    long idx = (long)(b-14208)*4096 + (long)tid*16;  // over [HD][512] ext cols
    int hrow = (int)(idx >> 9); int c = (int)(idx & 511);
    u16* d = Wdx + (size_t)hrow*KXD + FD + c;
    if (c < 128) {            // one full (e, r0..15) row per 16-chunk
      const float* s = Bd + ((size_t)(c>>4)*HD + hrow)*16;
      v4f a0 = *(const v4f*)s,     a1 = *(const v4f*)(s+4);
      v4f a2 = *(const v4f*)(s+8), a3 = *(const v4f*)(s+12);
      *(v8s*)d     = pack8(a0, a1);
      *(v8s*)(d+8) = pack8(a2, a3);
    } else {
      v8s z = {0,0,0,0,0,0,0,0};
      *(v8s*)d = z; *(v8s*)(d+8) = z;
    }
  } else {
    long i = (long)(b-14464)*4096 + (long)tid*16;
    v4f z = {0.f,0.f,0.f,0.f};
    *(v4f*)(hAx+i) = z; *(v4f*)(hAx+i+4) = z;
    *(v4f*)(hAx+i+8) = z; *(v4f*)(hAx+i+12) = z;
  }
}

// ---------- router + gather ----------
__global__ __launch_bounds__(64)
void router_kernel(const float* __restrict__ h, const float* __restrict__ gw,
                   int* __restrict__ sel, int* __restrict__ count,
                   int* __restrict__ listTok, float* __restrict__ listW) {
  int t = blockIdx.x, lane = threadIdx.x;
  const float* hp = h + (size_t)t * HD;
  float acc[8] = {0,0,0,0,0,0,0,0};
  for (int i = lane; i < HD; i += 64) {
    float hv = hp[i];
    #pragma unroll
    for (int e = 0; e < 8; ++e) acc[e] += hv * gw[e*HD + i];
  }
  #pragma unroll
  for (int off = 32; off > 0; off >>= 1) {
    #pragma unroll
    for (int e = 0; e < 8; ++e) acc[e] += __shfl_xor(acc[e], off, 64);
  }
  if (lane == 0) {
    int e0 = -1, e1 = -1; float b0 = -1e30f, b1 = -1e30f;
    #pragma unroll
    for (int e = 0; e < 8; ++e) {
      float v = acc[e];
      if (v > b0) { b1 = b0; e1 = e0; b0 = v; e0 = e; }
      else if (v > b1) { b1 = v; e1 = e; }
    }
    float p1 = __expf(b1 - b0);            // p0 = 1
    float w0 = 1.f / (1.f + p1);
    float w1 = p1 * w0;
    sel[2*t] = e0; sel[2*t+1] = e1;
    int pos0 = atomicAdd(&count[e0], 1);
    listTok[e0*TT + pos0] = t;           listW[e0*TT + pos0] = w0;
    int pos1 = atomicAdd(&count[e1], 1);
    listTok[e1*TT + pos1] = t | (1<<20); listW[e1*TT + pos1] = w1;
  }
}

// ---------- 128x128x64 bf16 GEMM (m97 structure), C = A @ B^T, split-K atomic ----------
__global__ __launch_bounds__(256)
void gemm128a(const u16* __restrict__ A, const u16* __restrict__ B, float* __restrict__ Cout,
              int K, int ldc) {
  __shared__ u16 As[128*64];
  __shared__ u16 Bs[128*64];
  const int tid  = threadIdx.x;
  const int lane = tid & 63, wid = tid >> 6;
  const int gx = gridDim.x;
  const int lin = blockIdx.y * gx + blockIdx.x;
  const int chunk = (gx * gridDim.y) >> 3;
  const int wg = (lin & 7) * chunk + (lin >> 3);
  const int m0 = (wg % gx) * 128, n0 = (wg / gx) * 128;
  const int kc = K / gridDim.z;
  const int kbeg = blockIdx.z * kc;
  const int wr = wid >> 1, wc = wid & 1;
  const int lrow = lane >> 3, lcol = (lane & 7) * 8;
  v4f acc[4][4];
  #pragma unroll
  for (int mi = 0; mi < 4; ++mi)
    #pragma unroll
    for (int ni = 0; ni < 4; ++ni) acc[mi][ni] = (v4f){0.f,0.f,0.f,0.f};

  for (int k0 = kbeg; k0 < kbeg + kc; k0 += 64) {
    #pragma unroll
    for (int it = 0; it < 4; ++it) {
      int seg = wid*4 + it;
      int row = seg*8 + lrow;
      gload_lds16(A + (size_t)(m0+row)*K + k0 + lcol, As + seg*512);
      gload_lds16(B + (size_t)(n0+row)*K + k0 + lcol, Bs + seg*512);
    }
    __syncthreads();
    #pragma unroll
    for (int kk = 0; kk < 64; kk += 32) {
      v8s af[4], bfr[4];
      #pragma unroll
      for (int mi = 0; mi < 4; ++mi)
        af[mi] = *(const v8s*)(As + (wr*64 + mi*16 + (lane&15))*64 + kk + (lane>>4)*8);
      #pragma unroll
      for (int ni = 0; ni < 4; ++ni)
        bfr[ni] = *(const v8s*)(Bs + (wc*64 + ni*16 + (lane&15))*64 + kk + (lane>>4)*8);
      #pragma unroll
      for (int mi = 0; mi < 4; ++mi)
        #pragma unroll
        for (int ni = 0; ni < 4; ++ni)
          acc[mi][ni] = __builtin_amdgcn_mfma_f32_16x16x32_bf16(af[mi], bfr[ni], acc[mi][ni], 0, 0, 0);
    }
    __syncthreads();
  }

  #pragma unroll
  for (int mi = 0; mi < 4; ++mi)
    #pragma unroll
    for (int j = 0; j < 4; ++j) {
      int row = m0 + wr*64 + mi*16 + (lane>>4)*4 + j;
      size_t base = (size_t)row*ldc + n0 + wc*64 + (lane&15);
      #pragma unroll
      for (int ni = 0; ni < 4; ++ni)
        atomicAdd(&Cout[base + ni*16], acc[mi][ni][j]);
    }
}

// ---------- 256x256 8-phase bf16 GEMM, C = A @ B^T  (T1+T2+T3+T4+T5) ----------
// MODE 0: bf16 store. MODE 3: fp32 per-z-slice partial store (no atomics).
template<int MODE>
__global__ __launch_bounds__(512, 2)
void gemm256(const u16* __restrict__ A, const u16* __restrict__ B, void* __restrict__ Cout,
             int ldk, int kchunk, int ldc) {
  __shared__ u16 lds[2][2][2][8192];
  const int tid = threadIdx.x, lane = tid & 63, wid = tid >> 6;
  const int gx = gridDim.x;
  const int nwg = gx * gridDim.y;
  const int lin = blockIdx.y * gx + blockIdx.x;
  const int chunk = nwg >> 3;                       // nwg % 8 == 0 by construction
  const int wg = (lin & 7) * chunk + (lin >> 3);    // bijective XCD swizzle
  const int m0 = (wg % gx) * 256, n0 = (wg / gx) * 256;
  const long kbeg = (long)blockIdx.z * kchunk;
  const int NK = kchunk >> 6, NI = NK >> 1;         // NK even
  const int wr = wid >> 2, wc = wid & 3;

  const int s_r = (wid << 4) + (lane >> 3);
  const int s_c = lane & 7;

  auto STAGE = [&](int slot, int ab, int half, const u16* M, int rc0, int kt) {
    const u16* g0 = M + (size_t)(rc0 + half*128 + s_r) * ldk + kbeg + kt*64 + ((s_c ^ (s_r & 7)) << 3);
    gload_lds16(g0, &lds[slot][ab][half][wid << 10]);
    const int r1 = s_r + 8;
    const u16* g1 = M + (size_t)(rc0 + half*128 + r1) * ldk + kbeg + kt*64 + ((s_c ^ (r1 & 7)) << 3);
    gload_lds16(g1, &lds[slot][ab][half][(wid << 10) + 512]);
  };
  auto LDA = [&](int slot, int mf, int c16b) -> v8s {
    int rr = (mf << 4) + (lane & 15);
    return *(const v8s*)&lds[slot][0][wr][rr*64 + (((c16b + (lane >> 4)) ^ (rr & 7)) << 3)];
  };
  auto LDB = [&](int slot, int nf, int c16b) -> v8s {
    int row = (wc << 6) + (nf << 4) + (lane & 15);
    int rr = row & 127;
    return *(const v8s*)&lds[slot][1][row >> 7][rr*64 + (((c16b + (lane >> 4)) ^ (rr & 7)) << 3)];
  };

  v4f acc[8][4];
  #pragma unroll
  for (int mf = 0; mf < 8; ++mf)
    #pragma unroll
    for (int nf = 0; nf < 4; ++nf) acc[mf][nf] = (v4f){0.f,0.f,0.f,0.f};

  STAGE(0,1,0,B,n0,0); STAGE(0,1,1,B,n0,0);
  STAGE(0,0,0,A,m0,0); STAGE(0,0,1,A,m0,0);
  STAGE(1,1,0,B,n0,1); STAGE(1,1,1,B,n0,1);
  vm_wait4();
  barrier_pin();

  for (int i = 0; i < NI; ++i) {
    const int kt0 = 2*i, kt1 = kt0 + 1;
    const int kt2c = (kt0 + 2 < NK) ? kt0 + 2 : kt0;
    const bool s45 = (kt0 + 2 < NK), s67 = (kt1 + 2 < NK);
    v8s bf[4][2], af[2][2];
    // ---- phase 0 (slot0, q0)
    #pragma unroll
    for (int nf = 0; nf < 4; ++nf) { bf[nf][0] = LDB(0,nf,0); bf[nf][1] = LDB(0,nf,4); }
    af[0][0]=LDA(0,0,0); af[0][1]=LDA(0,0,4); af[1][0]=LDA(0,1,0); af[1][1]=LDA(0,1,4);
    STAGE(1,0,0,A,m0,kt1);
    barrier_pin(); mmq<0>(acc,af,bf); barrier_pin();
    // ---- phase 1 (slot0, q1)
    af[0][0]=LDA(0,2,0); af[0][1]=LDA(0,2,4); af[1][0]=LDA(0,3,0); af[1][1]=LDA(0,3,4);
    STAGE(1,0,1,A,m0,kt1);
    barrier_pin(); mmq<1>(acc,af,bf); barrier_pin();
    // ---- phase 2 (slot0, q2)
    af[0][0]=LDA(0,4,0); af[0][1]=LDA(0,4,4); af[1][0]=LDA(0,5,0); af[1][1]=LDA(0,5,4);
    STAGE(0,1,0,B,n0,kt2c);
    barrier_pin(); mmq<2>(acc,af,bf); barrier_pin();
    // ---- phase 3 (slot0, q3)
    af[0][0]=LDA(0,6,0); af[0][1]=LDA(0,6,4); af[1][0]=LDA(0,7,0); af[1][1]=LDA(0,7,4);
    STAGE(0,1,1,B,n0,kt2c);
    vm_wait4();
    barrier_pin(); mmq<3>(acc,af,bf); barrier_pin();
    // ---- phase 4 (slot1, q0)
    #pragma unroll
    for (int nf = 0; nf < 4; ++nf) { bf[nf][0] = LDB(1,nf,0); bf[nf][1] = LDB(1,nf,4); }
    af[0][0]=LDA(1,0,0); af[0][1]=LDA(1,0,4); af[1][0]=LDA(1,1,0); af[1][1]=LDA(1,1,4);
    if (s45) STAGE(0,0,0,A,m0,kt0+2);
    barrier_pin(); mmq<0>(acc,af,bf); barrier_pin();
    // ---- phase 5 (slot1, q1)
    af[0][0]=LDA(1,2,0); af[0][1]=LDA(1,2,4); af[1][0]=LDA(1,3,0); af[1][1]=LDA(1,3,4);
    if (s45) STAGE(0,0,1,A,m0,kt0+2);
    barrier_pin(); mmq<1>(acc,af,bf); barrier_pin();
    // ---- phase 6 (slot1, q2)
    af[0][0]=LDA(1,4,0); af[0][1]=LDA(1,4,4); af[1][0]=LDA(1,5,0); af[1][1]=LDA(1,5,4);
    if (s67) STAGE(1,1,0,B,n0,kt1+2);
    barrier_pin(); mmq<2>(acc,af,bf); barrier_pin();
    // ---- phase 7 (slot1, q3)
    af[0][0]=LDA(1,6,0); af[0][1]=LDA(1,6,4); af[1][0]=LDA(1,7,0); af[1][1]=LDA(1,7,4);
    if (s67) STAGE(1,1,1,B,n0,kt1+2);
    vm_wait4();
    barrier_pin(); mmq<3>(acc,af,bf); barrier_pin();
  }
  vm_wait0();

  if (MODE == 0) {
    u16* C = (u16*)Cout;
    #pragma unroll
    for (int mf = 0; mf < 8; ++mf)
      #pragma unroll
      for (int j = 0; j < 4; ++j) {
        int row = m0 + wr*128 + mf*16 + (lane>>4)*4 + j;
        size_t base = (size_t)row*ldc + n0 + wc*64 + (lane&15);
        #pragma unroll
        for (int nf = 0; nf < 4; ++nf)
          C[base + nf*16] = f2b(acc[mf][nf][j]);
      }
  } else {
    float* C = (float*)Cout + (size_t)blockIdx.z * TT * HD;   // per-slice partial
    #pragma unroll
    for (int mf = 0; mf < 8; ++mf)
      #pragma unroll
      for (int j = 0; j < 4; ++j) {
        int row = m0 + wr*128 + mf*16 + (lane>>4)*4 + j;
        size_t base = (size_t)row*ldc + n0 + wc*64 + (lane&15);
        #pragma unroll
        for (int nf = 0; nf < 4; ++nf)
          C[base + nf*16] = acc[mf][nf][j];
      }
  }
}

// ---------- reduce: out = sum of 4 fp32 partials ----------
__global__ __launch_bounds__(256)
void reduce4_kernel(const float* __restrict__ P, float* __restrict__ out) {
  long i = ((long)blockIdx.x * 256 + threadIdx.x) * 4;
  const size_t S = (size_t)TT * HD;
  v4f s = *(const v4f*)(P + i);
  s = s + *(const v4f*)(P + S + i);
  s = s + *(const v4f*)(P + 2*S + i);
  s = s + *(const v4f*)(P + 3*S + i);
  *(v4f*)(out + i) = s;
}

// ---------- expert kernel (T14 async-stage prefetch; bf16 weights direct) ----------
static constexpr int HA_LD = 40;
static constexpr int AW_LD = 72;
static constexpr int CT_LD = 72;

__global__ __launch_bounds__(256)
void expert_kernel(const u16* __restrict__ CGU,                                // [TT][NXE]
                   const float* __restrict__ hAx,                              // [TT][256] fp32
                   const u16* __restrict__ Bgb, const u16* __restrict__ Bub,   // [E][F][16] bf16
                   const u16* __restrict__ Adb,                                // [E][16][F] bf16
                   const int* __restrict__ count, const int* __restrict__ listTok,
                   const float* __restrict__ listW,
                   u16* __restrict__ actw0, u16* __restrict__ actw1,           // [TT+1][F]
                   float* __restrict__ cC) {                                   // [TT+1][2][16]
  const int e = blockIdx.y, g = blockIdx.x, fb = blockIdx.z;
  const int n = count[e];
  if (g*16 >= n) return;
  const int tid = threadIdx.x, lane = tid & 63, w = tid >> 6;
  __shared__ u16 hAg[16*HA_LD], hAu[16*HA_LD];
  __shared__ u16 AWs[4][16*AW_LD];
  __shared__ u16 cgT[4][16*CT_LD], cuT[4][16*CT_LD];
  __shared__ int sTok[16], sSlot[16];
  __shared__ float sW[16];
  __shared__ float dAred[4][256];

  if (tid < 16) {
    int idx = g*16 + tid;
    if (idx < n) {
      int ent = listTok[e*TT + idx];
      sTok[tid] = ent & 0xFFFF; sSlot[tid] = (ent >> 20) & 1; sW[tid] = listW[e*TT + idx];
    } else { sTok[tid] = TT; sSlot[tid] = 0; sW[tid] = 0.f; }
  }
  __syncthreads();
  if (tid < 128) {   // stage hA (both tensors) from hAx fp32, zero-pad K 16..31
    int tensor = tid >> 6;
    int sub = tid & 63;
    int row = sub >> 2, c8 = (sub & 3) * 8;
    int trd = min(sTok[row], TT - 1);
    u16 vals[8];
    if (c8 < 16) {
      const float* src = hAx + (size_t)trd*256 + tensor*128 + e*NR + c8;
      v4f a = *(const v4f*)src, b = *(const v4f*)(src + 4);
      v8s p = pack8(a, b);
      #pragma unroll
      for (int q = 0; q < 8; ++q) vals[q] = (u16)p[q];
    } else {
      #pragma unroll
      for (int q = 0; q < 8; ++q) vals[q] = 0;
    }
    u16* dst = (tensor ? hAu : hAg) + row*HA_LD + c8;
    #pragma unroll
    for (int q = 0; q < 8; ++q) dst[q] = vals[q];
  }
  __syncthreads();

  int tR[4], slR[4]; float wR[4];
  #pragma unroll
  for (int j = 0; j < 4; ++j) {
    int r = (lane>>4)*4 + j;
    tR[j] = sTok[r]; slR[j] = sSlot[r]; wR[j] = sW[r];
  }
  const int khalf = lane >> 4;
  v8s afg = *(const v8s*)(hAg + (lane&15)*HA_LD + khalf*8);
  v8s afu = *(const v8s*)(hAu + (lane&15)*HA_LD + khalf*8);
  v4f accDA = (v4f){0.f,0.f,0.f,0.f};
  u16* aww = AWs[w]; u16* cgw = cgT[w]; u16* cuw = cuT[w];
  const v8s zero8 = {0,0,0,0,0,0,0,0};
  const u16* BgE = Bgb + (size_t)e*FD*16;
  const u16* BuE = Bub + (size_t)e*FD*16;
  const u16* AdE = Adb + (size_t)e*16*FD;

  // per-lane coalesced-store coords (from aww)
  const int srj = lane >> 2, sc = (lane & 3) * 16;

  // T14 prefetch state: each lane stages 2 rows x (cg,cu) per chunk
  const int srow = lane >> 3, c8s = (lane & 7) * 8;
  const size_t trdA = (size_t)min(sTok[srow], TT - 1);
  const size_t trdB = (size_t)min(sTok[srow + 8], TT - 1);
  v8s rg0, rg1, ru0, ru1;
  auto LOADC = [&](int f0) {
    rg0 = *(const v8s*)(CGU + trdA*NXE + f0 + c8s);
    ru0 = *(const v8s*)(CGU + trdA*NXE + CU_OFF + f0 + c8s);
    rg1 = *(const v8s*)(CGU + trdB*NXE + f0 + c8s);
    ru1 = *(const v8s*)(CGU + trdB*NXE + CU_OFF + f0 + c8s);
  };
  auto WRITEC = [&]() {
    *(v8s*)(cgw + srow*CT_LD + c8s)     = rg0;
    *(v8s*)(cgw + (srow+8)*CT_LD + c8s) = rg1;
    *(v8s*)(cuw + srow*CT_LD + c8s)     = ru0;
    *(v8s*)(cuw + (srow+8)*CT_LD + c8s) = ru1;
  };

  const int ch_beg = fb*32 + w, ch_end = fb*32 + 32;
  LOADC(ch_beg * 64);
  WRITEC();
  for (int ch = ch_beg; ch < ch_end; ch += 4) {   // 64-wide f-chunks, wave-private
    int f0 = ch * 64;
    const bool pf = (ch + 4 < ch_end);
    if (pf) LOADC((ch + 4) * 64);                 // issue next chunk early (T14)
    v4f dg[4], du[4];
    #pragma unroll
    for (int nf = 0; nf < 4; ++nf) {   // B-fragments direct from global bf16 (L2-hot)
      int f = f0 + nf*16 + (lane & 15);
      v8s bgf = (khalf < 2) ? *(const v8s*)(BgE + (size_t)f*16 + khalf*8) : zero8;
      dg[nf] = __builtin_amdgcn_mfma_f32_16x16x32_bf16(afg, bgf, (v4f){0.f,0.f,0.f,0.f}, 0, 0, 0);
      v8s buf = (khalf < 2) ? *(const v8s*)(BuE + (size_t)f*16 + khalf*8) : zero8;
      du[nf] = __builtin_amdgcn_mfma_f32_16x16x32_bf16(afu, buf, (v4f){0.f,0.f,0.f,0.f}, 0, 0, 0);
    }
    #pragma unroll
    for (int nf = 0; nf < 4; ++nf) {
      #pragma unroll
      for (int j = 0; j < 4; ++j) {
        int rj = (lane>>4)*4 + j;
        int fi = nf*16 + (lane&15);
        float cgv = b2f(cgw[rj*CT_LD + fi]);
        float cuv = b2f(cuw[rj*CT_LD + fi]);
        float gv = cgv + 2.f * dg[nf][j];
        float uv = cuv + 2.f * du[nf][j];
        float a  = gv * __builtin_amdgcn_rcpf(1.f + __expf(-gv)) * uv;   // silu(g)*u
        aww[rj*AW_LD + fi] = f2b(wR[j] * a);        // LDS only; global store below
      }
    }
    { // coalesced global store of weighted act from aww (4 x v8s per lane)
      int st = sTok[srj], ss = sSlot[srj];
      u16* dst = (ss ? actw1 : actw0) + (size_t)st*FD + f0 + sc;
      *(v8s*)dst       = *(const v8s*)(aww + srj*AW_LD + sc);
      *(v8s*)(dst + 8) = *(const v8s*)(aww + srj*AW_LD + sc + 8);
    }
    #pragma unroll
    for (int ks = 0; ks < 2; ++ks) {   // dA accumulate: [16 tok] x [16 r] over K=64
      v8s aA = *(const v8s*)(aww + (lane&15)*AW_LD + ks*32 + khalf*8);
      v8s bA = *(const v8s*)(AdE + (size_t)(lane&15)*FD + f0 + ks*32 + khalf*8);
      accDA = __builtin_amdgcn_mfma_f32_16x16x32_bf16(aA, bA, accDA, 0, 0, 0);
    }
    if (pf) WRITEC();                              // land next chunk after compute consumed LDS
  }
  #pragma unroll
  for (int j = 0; j < 4; ++j)
    dAred[w][((lane>>4)*4 + j)*16 + (lane&15)] = accDA[j];
  __syncthreads();
  {
    int row = tid >> 4, col = tid & 15;
    float s2 = dAred[0][row*16+col] + dAred[1][row*16+col] + dAred[2][row*16+col] + dAred[3][row*16+col];
    atomicAdd(&cC[((size_t)sTok[row]*2 + sSlot[row])*16 + col], 2.f * s2);
  }
}

// ---------- combine: abx[t] = [actw0+actw1 (bf16), scattered c coefs, zeros] ----------
__global__ __launch_bounds__(256)
void combine2_kernel(const u16* __restrict__ a0, const u16* __restrict__ a1,
                     const float* __restrict__ cC, const int* __restrict__ sel,
                     u16* __restrict__ abx) {
  int t = blockIdx.x, tid = threadIdx.x;
  const u16* p0 = a0 + (size_t)t * FD;
  const u16* p1 = a1 + (size_t)t * FD;
  u16* po = abx + (size_t)t * KXD;
  for (int i = tid * 8; i < FD; i += 256 * 8) {
    v8s x = *(const v8s*)(p0 + i);
    v8s y = *(const v8s*)(p1 + i);
    v8s o;
    #pragma unroll
    for (int j = 0; j < 8; ++j) o[j] = (short)f2b(b2f((u16)x[j]) + b2f((u16)y[j]));
    *(v8s*)(po + i) = o;
  }
  for (int c = tid; c < 512; c += 256) {  // ext cols; c>=128 zeroed
    float v = 0.f;
    if (c < 128) {
      int e_i = c >> 4, r = c & 15;
      if (sel[2*t]     == e_i) v += cC[((size_t)t*2 + 0)*16 + r];
      if (sel[2*t + 1] == e_i) v += cC[((size_t)t*2 + 1)*16 + r];
    }
    po[FD + c] = f2b(v);
  }
}

// ---------- launch ----------
extern "C" void kernel_launch(void* const* d_in, const int* in_sizes, int n_in,
                              void* d_out, int out_size, void* d_ws, size_t ws_size,
                              hipStream_t stream) {
  (void)in_sizes; (void)n_in; (void)out_size; (void)ws_size;
  const float* h  = (const float*)d_in[0];
  const float* gw = (const float*)d_in[1];
  const float* Wg = (const float*)d_in[2];
  const float* Wu = (const float*)d_in[3];
  const float* Wd = (const float*)d_in[4];
  const float* Ag = (const float*)d_in[5];
  const float* Bg = (const float*)d_in[6];
  const float* Au = (const float*)d_in[7];
  const float* Bu = (const float*)d_in[8];
  const float* Ad = (const float*)d_in[9];
  const float* Bd = (const float*)d_in[10];

  char* ws = (char*)d_ws;
  size_t off = 0;
  auto alloc = [&](size_t bytes) { size_t c = off; off += (bytes + 255) & ~(size_t)255; return c; };
  u16*  hb     = (u16*)(ws + alloc((size_t)TT*HD*2));             // 8 MB
  u16*  Bgux   = (u16*)(ws + alloc((size_t)(TT+1)*FD*2*2));       // 67.2 MB [Wg|Wu]; actw0/1; down partials
  u16*  Agu    = (u16*)(ws + alloc((size_t)256*HD*2));            // 1 MB [Ag all|Au all]
  u16*  Wdx    = (u16*)(ws + alloc((size_t)HD*KXD*2));            // 35.7 MB [HD][KXD]
  u16*  CGU    = (u16*)(ws + alloc((size_t)TT*NXE*2));            // 64 MB [TT][NXE]; later abx [TT][KXD]
  u16*  Bgb    = (u16*)(ws + alloc((size_t)NE*FD*16*2));          // 2 MB bf16
  u16*  Bub    = (u16*)(ws + alloc((size_t)NE*FD*16*2));          // 2 MB
  u16*  Adb    = (u16*)(ws + alloc((size_t)NE*16*FD*2));          // 2 MB
  float* hAx   = (float*)(ws + alloc((size_t)TT*256*4));          // 2 MB
  float* cC    = (float*)(ws + alloc((size_t)(TT+1)*2*16*4));
  int*  sel    = (int*)(ws + alloc((size_t)TT*2*4));
  int*  count  = (int*)(ws + alloc(256));
  int*  listTok= (int*)(ws + alloc((size_t)NE*TT*4));
  float* listW = (float*)(ws + alloc((size_t)NE*TT*4));
  u16*  actw0  = Bgux;                                  // alias: Bgux dead after gate/up GEMMs
  u16*  actw1  = Bgux + (size_t)(TT+1)*FD;
  u16*  abx    = CGU;                                   // alias: CGU dead after expert_kernel
  float* parts = (float*)Bgux;                          // alias: actw dead after combine2 (64 MB <= 67.2)

  hipMemsetAsync(count, 0, NE*sizeof(int), stream);
  hipMemsetAsync(cC, 0, (size_t)(TT+1)*2*16*4, stream);

  // one mega-prep: all casts + Bd-ext + hAx zero
  prep_kernel<<<PREP_BLOCKS, 256, 0, stream>>>(h, Wg, Wu, Wd, Ag, Au, Bg, Bu, Ad, Bd,
                                               hb, Bgux, Agu, Wdx, Bgb, Bub, Adb, hAx);

  router_kernel<<<TT, 64, 0, stream>>>(h, gw, sel, count, listTok, listW);

  // hAx = h @ [Ag;Au]^T  (M=2048, N=256, K=2048, split-K=8 -> 256 blocks)
  gemm128a<<<dim3(16, 2, 8), 256, 0, stream>>>(hb, Agu, hAx, HD, 256);

  // gate: CG = h @ Wg^T   (M=2048, N=8192, K=2048) -> 256 blocks = 1 exact round
  gemm256<0><<<dim3(8, 32, 1), 512, 0, stream>>>(hb, Bgux, CGU, HD, HD, NXE);
  // up:   CU = h @ Wu^T   -> 256 blocks = 1 exact round (writes CGU cols FD..)
  gemm256<0><<<dim3(8, 32, 1), 512, 0, stream>>>(hb, Bgux + (size_t)FD*HD, CGU + CU_OFF, HD, HD, NXE);

  // per-expert: deltas, act, weighted act into slot buffers (aliasing Bgux), c coefs
  expert_kernel<<<dim3(128, NE, 4), 256, 0, stream>>>(CGU, hAx, Bgb, Bub, Adb, count, listTok, listW,
                                                      actw0, actw1, cC);

  // abx = [actw0+actw1, c-scatter, zeros]  (writes into the dead CGU region)
  combine2_kernel<<<TT, 256, 0, stream>>>(actw0, actw1, cC, sel, abx);

  // partials[z] = abx @ Wdx^T slice z  (M=2048, N=2048, K=8704, split-K=4 -> 256 blocks, no atomics)
  gemm256<3><<<dim3(8, 8, 4), 512, 0, stream>>>(abx, Wdx, parts, KXD, KXD/4, HD);

  // out = sum of 4 partials
  reduce4_kernel<<<4096, 256, 0, stream>>>(parts, (float*)d_out);
}

// Round 10
// 453.735 us; speedup vs baseline: 1.0050x; 1.0050x over previous
//
#include <hip/hip_runtime.h>
#include <hip/hip_bf16.h>

typedef __attribute__((ext_vector_type(8))) short v8s;   // 8 x bf16 (as i16)
typedef __attribute__((ext_vector_type(4))) float v4f;
typedef unsigned short u16;

static constexpr int TT = 2048;        // tokens
static constexpr int HD = 2048;        // hidden
static constexpr int FD = 8192;        // ffn dim
static constexpr int NE = 8;           // experts
static constexpr int NR = 16;          // lora rank
static constexpr int NXE = 2*FD;       // 16384: merged [Wg | Wu] cols
static constexpr int CU_OFF = FD;      // up offset inside CGU row
static constexpr int KXD = FD + 512;   // 8704 = 136*64 ext K for down GEMM (34*64*4)

// ---------- helpers ----------
__device__ __forceinline__ u16 f2b(float f) {            // fp32 -> bf16 RNE
  union { float f; unsigned u; } v; v.f = f;
  unsigned r = v.u + 0x7FFFu + ((v.u >> 16) & 1u);
  return (u16)(r >> 16);
}
__device__ __forceinline__ float b2f(u16 h) {
  union { unsigned u; float f; } v; v.u = ((unsigned)h) << 16;
  return v.f;
}
__device__ __forceinline__ v8s pack8(v4f a, v4f b) {
  v8s r;
  r[0]=(short)f2b(a.x); r[1]=(short)f2b(a.y); r[2]=(short)f2b(a.z); r[3]=(short)f2b(a.w);
  r[4]=(short)f2b(b.x); r[5]=(short)f2b(b.y); r[6]=(short)f2b(b.z); r[7]=(short)f2b(b.w);
  return r;
}
__device__ __forceinline__ void gload_lds16(const void* g, void* l) {
  __builtin_amdgcn_global_load_lds(
      (const __attribute__((address_space(1))) unsigned int*)g,
      (__attribute__((address_space(3))) unsigned int*)l, 16, 0, 0);
}
__device__ __forceinline__ void barrier_pin() {
  __builtin_amdgcn_s_barrier();
  __builtin_amdgcn_sched_barrier(0);
}
__device__ __forceinline__ void vm_wait4() { asm volatile("s_waitcnt vmcnt(4)" ::: "memory"); }
__device__ __forceinline__ void vm_wait0() { asm volatile("s_waitcnt vmcnt(0)" ::: "memory"); }

template<int Q>
__device__ __forceinline__ void mmq(v4f (&acc)[8][4], const v8s (&af)[2][2], const v8s (&bf)[4][2]) {
  __builtin_amdgcn_s_setprio(1);
  #pragma unroll
  for (int m2 = 0; m2 < 2; ++m2)
    #pragma unroll
    for (int nf = 0; nf < 4; ++nf) {
      acc[Q*2+m2][nf] = __builtin_amdgcn_mfma_f32_16x16x32_bf16(af[m2][0], bf[nf][0], acc[Q*2+m2][nf], 0, 0, 0);
      acc[Q*2+m2][nf] = __builtin_amdgcn_mfma_f32_16x16x32_bf16(af[m2][1], bf[nf][1], acc[Q*2+m2][nf], 0, 0, 0);
    }
  __builtin_amdgcn_s_setprio(0);
}

// ---------- mega prep v3: 32 fp32/thread (8 loads in flight) ----------
// block = 8192 elems (except Bd-ext 4096, hAx 8192 fp32). ranges:
//  [0,512) h  [512,2560) Wg  [2560,4608) Wu  [4608,6656) Wd->Wdx(ld)
//  [6656,6688) Ag  [6688,6720) Au  [6720,6848) Bg  [6848,6976) Bu
//  [6976,7104) Ad  [7104,7360) Bd->Wdx ext  [7360,7424) zero hAx
static constexpr int PREP_BLOCKS = 7424;
__global__ __launch_bounds__(256)
void prep_kernel(const float* __restrict__ h, const float* __restrict__ Wg,
                 const float* __restrict__ Wu, const float* __restrict__ Wd,
                 const float* __restrict__ Ag, const float* __restrict__ Au,
                 const float* __restrict__ Bg, const float* __restrict__ Bu,
                 const float* __restrict__ Ad, const float* __restrict__ Bd,
                 u16* __restrict__ hb, u16* __restrict__ Bgux, u16* __restrict__ Agu,
                 u16* __restrict__ Wdx, u16* __restrict__ Bgb, u16* __restrict__ Bub,
                 u16* __restrict__ Adb, float* __restrict__ hAx) {
  const int b = blockIdx.x, tid = threadIdx.x;
  auto cast32at = [&](const float* s, u16* d) {
    v4f a0 = *(const v4f*)(s),    a1 = *(const v4f*)(s+4);
    v4f a2 = *(const v4f*)(s+8),  a3 = *(const v4f*)(s+12);
    v4f a4 = *(const v4f*)(s+16), a5 = *(const v4f*)(s+20);
    v4f a6 = *(const v4f*)(s+24), a7 = *(const v4f*)(s+28);
    *(v8s*)(d)    = pack8(a0, a1);
    *(v8s*)(d+8)  = pack8(a2, a3);
    *(v8s*)(d+16) = pack8(a4, a5);
    *(v8s*)(d+24) = pack8(a6, a7);
  };
  auto cast32 = [&](const float* s, u16* d, long blk) {
    long i = blk*8192 + (long)tid*32;
    cast32at(s+i, d+i);
  };
  if (b < 512) { cast32(h, hb, b); }
  else if (b < 2560) { cast32(Wg, Bgux, b-512); }
  else if (b < 4608) { cast32(Wu, Bgux + (size_t)FD*HD, b-2560); }
  else if (b < 6656) {
    long idx = (long)(b-4608)*8192 + (long)tid*32;   // over [HD][FD]
    long r = idx >> 13; int c = (int)(idx & 8191);
    cast32at(Wd + r*FD + c, Wdx + r*KXD + c);
  }
  else if (b < 6688) { cast32(Ag, Agu, b-6656); }
  else if (b < 6720) { cast32(Au, Agu + (size_t)128*HD, b-6688); }
  else if (b < 6848) { cast32(Bg, Bgb, b-6720); }
  else if (b < 6976) { cast32(Bu, Bub, b-6848); }
  else if (b < 7104) { cast32(Ad, Adb, b-6976); }
  else if (b < 7360) {
    long idx = (long)(b-7104)*4096 + (long)tid*16;   // over [HD][512] ext cols
    int hrow = (int)(idx >> 9); int c = (int)(idx & 511);
    u16* d = Wdx + (size_t)hrow*KXD + FD + c;
    if (c < 128) {            // one full (e, r0..15) row per 16-chunk
      const float* s = Bd + ((size_t)(c>>4)*HD + hrow)*16;
      v4f a0 = *(const v4f*)s,     a1 = *(const v4f*)(s+4);
      v4f a2 = *(const v4f*)(s+8), a3 = *(const v4f*)(s+12);
      *(v8s*)d     = pack8(a0, a1);
      *(v8s*)(d+8) = pack8(a2, a3);
    } else {
      v8s z = {0,0,0,0,0,0,0,0};
      *(v8s*)d = z; *(v8s*)(d+8) = z;
    }
  } else {
    long i = (long)(b-7360)*8192 + (long)tid*32;
    v4f z = {0.f,0.f,0.f,0.f};
    #pragma unroll
    for (int q = 0; q < 8; ++q) *(v4f*)(hAx+i+q*4) = z;
  }
}

// ---------- router + gather ----------
__global__ __launch_bounds__(64)
void router_kernel(const float* __restrict__ h, const float* __restrict__ gw,
                   int* __restrict__ sel, int* __restrict__ count,
                   int* __restrict__ listTok, float* __restrict__ listW) {
  int t = blockIdx.x, lane = threadIdx.x;
  const float* hp = h + (size_t)t * HD;
  float acc[8] = {0,0,0,0,0,0,0,0};
  for (int i = lane; i < HD; i += 64) {
    float hv = hp[i];
    #pragma unroll
    for (int e = 0; e < 8; ++e) acc[e] += hv * gw[e*HD + i];
  }
  #pragma unroll
  for (int off = 32; off > 0; off >>= 1) {
    #pragma unroll
    for (int e = 0; e < 8; ++e) acc[e] += __shfl_xor(acc[e], off, 64);
  }
  if (lane == 0) {
    int e0 = -1, e1 = -1; float b0 = -1e30f, b1 = -1e30f;
    #pragma unroll
    for (int e = 0; e < 8; ++e) {
      float v = acc[e];
      if (v > b0) { b1 = b0; e1 = e0; b0 = v; e0 = e; }
      else if (v > b1) { b1 = v; e1 = e; }
    }
    float p1 = __expf(b1 - b0);            // p0 = 1
    float w0 = 1.f / (1.f + p1);
    float w1 = p1 * w0;
    sel[2*t] = e0; sel[2*t+1] = e1;
    int pos0 = atomicAdd(&count[e0], 1);
    listTok[e0*TT + pos0] = t;           listW[e0*TT + pos0] = w0;
    int pos1 = atomicAdd(&count[e1], 1);
    listTok[e1*TT + pos1] = t | (1<<20); listW[e1*TT + pos1] = w1;
  }
}

// ---------- 128x128x64 bf16 GEMM (m97 structure), C = A @ B^T, split-K atomic ----------
__global__ __launch_bounds__(256)
void gemm128a(const u16* __restrict__ A, const u16* __restrict__ B, float* __restrict__ Cout,
              int K, int ldc) {
  __shared__ u16 As[128*64];
  __shared__ u16 Bs[128*64];
  const int tid  = threadIdx.x;
  const int lane = tid & 63, wid = tid >> 6;
  const int gx = gridDim.x;
  const int lin = blockIdx.y * gx + blockIdx.x;
  const int chunk = (gx * gridDim.y) >> 3;
  const int wg = (lin & 7) * chunk + (lin >> 3);
  const int m0 = (wg % gx) * 128, n0 = (wg / gx) * 128;
  const int kc = K / gridDim.z;
  const int kbeg = blockIdx.z * kc;
  const int wr = wid >> 1, wc = wid & 1;
  const int lrow = lane >> 3, lcol = (lane & 7) * 8;
  v4f acc[4][4];
  #pragma unroll
  for (int mi = 0; mi < 4; ++mi)
    #pragma unroll
    for (int ni = 0; ni < 4; ++ni) acc[mi][ni] = (v4f){0.f,0.f,0.f,0.f};

  for (int k0 = kbeg; k0 < kbeg + kc; k0 += 64) {
    #pragma unroll
    for (int it = 0; it < 4; ++it) {
      int seg = wid*4 + it;
      int row = seg*8 + lrow;
      gload_lds16(A + (size_t)(m0+row)*K + k0 + lcol, As + seg*512);
      gload_lds16(B + (size_t)(n0+row)*K + k0 + lcol, Bs + seg*512);
    }
    __syncthreads();
    #pragma unroll
    for (int kk = 0; kk < 64; kk += 32) {
      v8s af[4], bfr[4];
      #pragma unroll
      for (int mi = 0; mi < 4; ++mi)
        af[mi] = *(const v8s*)(As + (wr*64 + mi*16 + (lane&15))*64 + kk + (lane>>4)*8);
      #pragma unroll
      for (int ni = 0; ni < 4; ++ni)
        bfr[ni] = *(const v8s*)(Bs + (wc*64 + ni*16 + (lane&15))*64 + kk + (lane>>4)*8);
      #pragma unroll
      for (int mi = 0; mi < 4; ++mi)
        #pragma unroll
        for (int ni = 0; ni < 4; ++ni)
          acc[mi][ni] = __builtin_amdgcn_mfma_f32_16x16x32_bf16(af[mi], bfr[ni], acc[mi][ni], 0, 0, 0);
    }
    __syncthreads();
  }

  #pragma unroll
  for (int mi = 0; mi < 4; ++mi)
    #pragma unroll
    for (int j = 0; j < 4; ++j) {
      int row = m0 + wr*64 + mi*16 + (lane>>4)*4 + j;
      size_t base = (size_t)row*ldc + n0 + wc*64 + (lane&15);
      #pragma unroll
      for (int ni = 0; ni < 4; ++ni)
        atomicAdd(&Cout[base + ni*16], acc[mi][ni][j]);
    }
}

// ---------- 256x256 8-phase bf16 GEMM, C = A @ B^T  (T1+T2+T3+T4+T5) ----------
// MODE 0: bf16 store. MODE 3: fp32 per-z-slice partial store (no atomics).
template<int MODE>
__global__ __launch_bounds__(512, 2)
void gemm256(const u16* __restrict__ A, const u16* __restrict__ B, void* __restrict__ Cout,
             int ldk, int kchunk, int ldc) {
  __shared__ u16 lds[2][2][2][8192];
  const int tid = threadIdx.x, lane = tid & 63, wid = tid >> 6;
  const int gx = gridDim.x;
  const int nwg = gx * gridDim.y;
  const int lin = blockIdx.y * gx + blockIdx.x;
  const int chunk = nwg >> 3;                       // nwg % 8 == 0 by construction
  const int wg = (lin & 7) * chunk + (lin >> 3);    // bijective XCD swizzle
  const int m0 = (wg % gx) * 256, n0 = (wg / gx) * 256;
  const long kbeg = (long)blockIdx.z * kchunk;
  const int NK = kchunk >> 6, NI = NK >> 1;         // NK even
  const int wr = wid >> 2, wc = wid & 3;

  const int s_r = (wid << 4) + (lane >> 3);
  const int s_c = lane & 7;

  auto STAGE = [&](int slot, int ab, int half, const u16* M, int rc0, int kt) {
    const u16* g0 = M + (size_t)(rc0 + half*128 + s_r) * ldk + kbeg + kt*64 + ((s_c ^ (s_r & 7)) << 3);
    gload_lds16(g0, &lds[slot][ab][half][wid << 10]);
    const int r1 = s_r + 8;
    const u16* g1 = M + (size_t)(rc0 + half*128 + r1) * ldk + kbeg + kt*64 + ((s_c ^ (r1 & 7)) << 3);
    gload_lds16(g1, &lds[slot][ab][half][(wid << 10) + 512]);
  };
  auto LDA = [&](int slot, int mf, int c16b) -> v8s {
    int rr = (mf << 4) + (lane & 15);
    return *(const v8s*)&lds[slot][0][wr][rr*64 + (((c16b + (lane >> 4)) ^ (rr & 7)) << 3)];
  };
  auto LDB = [&](int slot, int nf, int c16b) -> v8s {
    int row = (wc << 6) + (nf << 4) + (lane & 15);
    int rr = row & 127;
    return *(const v8s*)&lds[slot][1][row >> 7][rr*64 + (((c16b + (lane >> 4)) ^ (rr & 7)) << 3)];
  };

  v4f acc[8][4];
  #pragma unroll
  for (int mf = 0; mf < 8; ++mf)
    #pragma unroll
    for (int nf = 0; nf < 4; ++nf) acc[mf][nf] = (v4f){0.f,0.f,0.f,0.f};

  STAGE(0,1,0,B,n0,0); STAGE(0,1,1,B,n0,0);
  STAGE(0,0,0,A,m0,0); STAGE(0,0,1,A,m0,0);
  STAGE(1,1,0,B,n0,1); STAGE(1,1,1,B,n0,1);
  vm_wait4();
  barrier_pin();

  for (int i = 0; i < NI; ++i) {
    const int kt0 = 2*i, kt1 = kt0 + 1;
    const int kt2c = (kt0 + 2 < NK) ? kt0 + 2 : kt0;
    const bool s45 = (kt0 + 2 < NK), s67 = (kt1 + 2 < NK);
    v8s bf[4][2], af[2][2];
    // ---- phase 0 (slot0, q0)
    #pragma unroll
    for (int nf = 0; nf < 4; ++nf) { bf[nf][0] = LDB(0,nf,0); bf[nf][1] = LDB(0,nf,4); }
    af[0][0]=LDA(0,0,0); af[0][1]=LDA(0,0,4); af[1][0]=LDA(0,1,0); af[1][1]=LDA(0,1,4);
    STAGE(1,0,0,A,m0,kt1);
    barrier_pin(); mmq<0>(acc,af,bf); barrier_pin();
    // ---- phase 1 (slot0, q1)
    af[0][0]=LDA(0,2,0); af[0][1]=LDA(0,2,4); af[1][0]=LDA(0,3,0); af[1][1]=LDA(0,3,4);
    STAGE(1,0,1,A,m0,kt1);
    barrier_pin(); mmq<1>(acc,af,bf); barrier_pin();
    // ---- phase 2 (slot0, q2)
    af[0][0]=LDA(0,4,0); af[0][1]=LDA(0,4,4); af[1][0]=LDA(0,5,0); af[1][1]=LDA(0,5,4);
    STAGE(0,1,0,B,n0,kt2c);
    barrier_pin(); mmq<2>(acc,af,bf); barrier_pin();
    // ---- phase 3 (slot0, q3)
    af[0][0]=LDA(0,6,0); af[0][1]=LDA(0,6,4); af[1][0]=LDA(0,7,0); af[1][1]=LDA(0,7,4);
    STAGE(0,1,1,B,n0,kt2c);
    vm_wait4();
    barrier_pin(); mmq<3>(acc,af,bf); barrier_pin();
    // ---- phase 4 (slot1, q0)
    #pragma unroll
    for (int nf = 0; nf < 4; ++nf) { bf[nf][0] = LDB(1,nf,0); bf[nf][1] = LDB(1,nf,4); }
    af[0][0]=LDA(1,0,0); af[0][1]=LDA(1,0,4); af[1][0]=LDA(1,1,0); af[1][1]=LDA(1,1,4);
    if (s45) STAGE(0,0,0,A,m0,kt0+2);
    barrier_pin(); mmq<0>(acc,af,bf); barrier_pin();
    // ---- phase 5 (slot1, q1)
    af[0][0]=LDA(1,2,0); af[0][1]=LDA(1,2,4); af[1][0]=LDA(1,3,0); af[1][1]=LDA(1,3,4);
    if (s45) STAGE(0,0,1,A,m0,kt0+2);
    barrier_pin(); mmq<1>(acc,af,bf); barrier_pin();
    // ---- phase 6 (slot1, q2)
    af[0][0]=LDA(1,4,0); af[0][1]=LDA(1,4,4); af[1][0]=LDA(1,5,0); af[1][1]=LDA(1,5,4);
    if (s67) STAGE(1,1,0,B,n0,kt1+2);
    barrier_pin(); mmq<2>(acc,af,bf); barrier_pin();
    // ---- phase 7 (slot1, q3)
    af[0][0]=LDA(1,6,0); af[0][1]=LDA(1,6,4); af[1][0]=LDA(1,7,0); af[1][1]=LDA(1,7,4);
    if (s67) STAGE(1,1,1,B,n0,kt1+2);
    vm_wait4();
    barrier_pin(); mmq<3>(acc,af,bf); barrier_pin();
  }
  vm_wait0();

  if (MODE == 0) {
    u16* C = (u16*)Cout;
    #pragma unroll
    for (int mf = 0; mf < 8; ++mf)
      #pragma unroll
      for (int j = 0; j < 4; ++j) {
        int row = m0 + wr*128 + mf*16 + (lane>>4)*4 + j;
        size_t base = (size_t)row*ldc + n0 + wc*64 + (lane&15);
        #pragma unroll
        for (int nf = 0; nf < 4; ++nf)
          C[base + nf*16] = f2b(acc[mf][nf][j]);
      }
  } else {
    float* C = (float*)Cout + (size_t)blockIdx.z * TT * HD;   // per-slice partial
    #pragma unroll
    for (int mf = 0; mf < 8; ++mf)
      #pragma unroll
      for (int j = 0; j < 4; ++j) {
        int row = m0 + wr*128 + mf*16 + (lane>>4)*4 + j;
        size_t base = (size_t)row*ldc + n0 + wc*64 + (lane&15);
        #pragma unroll
        for (int nf = 0; nf < 4; ++nf)
          C[base + nf*16] = acc[mf][nf][j];
      }
  }
}

// ---------- reduce: out = sum of 4 fp32 partials ----------
__global__ __launch_bounds__(256)
void reduce4_kernel(const float* __restrict__ P, float* __restrict__ out) {
  long i = ((long)blockIdx.x * 256 + threadIdx.x) * 4;
  const size_t S = (size_t)TT * HD;
  v4f s = *(const v4f*)(P + i);
  s = s + *(const v4f*)(P + S + i);
  s = s + *(const v4f*)(P + 2*S + i);
  s = s + *(const v4f*)(P + 3*S + i);
  *(v4f*)(out + i) = s;
}

// ---------- expert kernel v3: register double-buffer for ALL MFMA operands ----------
// grid (128 groups, NE, 8 f-blocks). Per block: 16 tokens x 1024 f-cols.
// Per wave: 4 chunks (64 f each), fully unrolled 2-state pipeline.
static constexpr int HA_LD = 40;
static constexpr int AW_LD = 72;
static constexpr int CT_LD = 72;

struct PF {      // per-chunk prefetch state (all v8s = 4 VGPR each; 14 total = 56 VGPR)
  v8s bg[4], bu[4], ad[2];
  v8s rg0, ru0, rg1, ru1;
};

__global__ __launch_bounds__(256)
void expert_kernel(const u16* __restrict__ CGU,                                // [TT][NXE]
                   const float* __restrict__ hAx,                              // [TT][256] fp32
                   const u16* __restrict__ Bgb, const u16* __restrict__ Bub,   // [E][F][16] bf16
                   const u16* __restrict__ Adb,                                // [E][16][F] bf16
                   const int* __restrict__ count, const int* __restrict__ listTok,
                   const float* __restrict__ listW,
                   u16* __restrict__ actw0, u16* __restrict__ actw1,           // [TT+1][F]
                   float* __restrict__ cC) {                                   // [TT+1][2][16]
  const int e = blockIdx.y, g = blockIdx.x, fb = blockIdx.z;
  const int n = count[e];
  if (g*16 >= n) return;
  const int tid = threadIdx.x, lane = tid & 63, w = tid >> 6;
  __shared__ u16 hAg[16*HA_LD], hAu[16*HA_LD];
  __shared__ u16 AWs[4][16*AW_LD];
  __shared__ u16 cgT[4][16*CT_LD], cuT[4][16*CT_LD];
  __shared__ int sTok[16], sSlot[16];
  __shared__ float sW[16];
  __shared__ float dAred[4][256];

  if (tid < 16) {
    int idx = g*16 + tid;
    if (idx < n) {
      int ent = listTok[e*TT + idx];
      sTok[tid] = ent & 0xFFFF; sSlot[tid] = (ent >> 20) & 1; sW[tid] = listW[e*TT + idx];
    } else { sTok[tid] = TT; sSlot[tid] = 0; sW[tid] = 0.f; }
  }
  __syncthreads();
  if (tid < 128) {   // stage hA (both tensors) from hAx fp32, zero-pad K 16..31
    int tensor = tid >> 6;
    int sub = tid & 63;
    int row = sub >> 2, c8 = (sub & 3) * 8;
    int trd = min(sTok[row], TT - 1);
    u16 vals[8];
    if (c8 < 16) {
      const float* src = hAx + (size_t)trd*256 + tensor*128 + e*NR + c8;
      v4f a = *(const v4f*)src, b = *(const v4f*)(src + 4);
      v8s p = pack8(a, b);
      #pragma unroll
      for (int q = 0; q < 8; ++q) vals[q] = (u16)p[q];
    } else {
      #pragma unroll
      for (int q = 0; q < 8; ++q) vals[q] = 0;
    }
    u16* dst = (tensor ? hAu : hAg) + row*HA_LD + c8;
    #pragma unroll
    for (int q = 0; q < 8; ++q) dst[q] = vals[q];
  }
  __syncthreads();

  int tR[4], slR[4]; float wR[4];
  #pragma unroll
  for (int j = 0; j < 4; ++j) {
    int r = (lane>>4)*4 + j;
    tR[j] = sTok[r]; slR[j] = sSlot[r]; wR[j] = sW[r];
  }
  const int khalf = lane >> 4;
  v8s afg = *(const v8s*)(hAg + (lane&15)*HA_LD + khalf*8);
  v8s afu = *(const v8s*)(hAu + (lane&15)*HA_LD + khalf*8);
  v4f accDA = (v4f){0.f,0.f,0.f,0.f};
  u16* aww = AWs[w]; u16* cgw = cgT[w]; u16* cuw = cuT[w];
  const v8s zero8 = {0,0,0,0,0,0,0,0};
  const u16* BgE = Bgb + (size_t)e*FD*16;
  const u16* BuE = Bub + (size_t)e*FD*16;
  const u16* AdE = Adb + (size_t)e*16*FD;

  // per-lane coalesced-store coords (from aww)
  const int srj = lane >> 2, sc = (lane & 3) * 16;
  // cg/cu staging coords (each lane loads 2 token rows x 8 cols)
  const int srow = lane >> 3, c8s = (lane & 7) * 8;
  const size_t trdA = (size_t)min(sTok[srow], TT - 1);
  const size_t trdB = (size_t)min(sTok[srow + 8], TT - 1);

  auto LOADPF = [&](int ch, PF& p) {
    const int f0 = ch * 64;
    #pragma unroll
    for (int nf = 0; nf < 4; ++nf) {
      int f = f0 + nf*16 + (lane & 15);
      p.bg[nf] = (khalf < 2) ? *(const v8s*)(BgE + (size_t)f*16 + khalf*8) : zero8;
      p.bu[nf] = (khalf < 2) ? *(const v8s*)(BuE + (size_t)f*16 + khalf*8) : zero8;
    }
    #pragma unroll
    for (int ks = 0; ks < 2; ++ks)
      p.ad[ks] = *(const v8s*)(AdE + (size_t)(lane&15)*FD + f0 + ks*32 + khalf*8);
    p.rg0 = *(const v8s*)(CGU + trdA*NXE + f0 + c8s);
    p.ru0 = *(const v8s*)(CGU + trdA*NXE + CU_OFF + f0 + c8s);
    p.rg1 = *(const v8s*)(CGU + trdB*NXE + f0 + c8s);
    p.ru1 = *(const v8s*)(CGU + trdB*NXE + CU_OFF + f0 + c8s);
  };

  auto COMPUTE = [&](int ch, const PF& p) {
    const int f0 = ch * 64;
    // land cg/cu into LDS (transpose for silu-phase reads)
    *(v8s*)(cgw + srow*CT_LD + c8s)     = p.rg0;
    *(v8s*)(cgw + (srow+8)*CT_LD + c8s) = p.rg1;
    *(v8s*)(cuw + srow*CT_LD + c8s)     = p.ru0;
    *(v8s*)(cuw + (srow+8)*CT_LD + c8s) = p.ru1;
    v4f dg[4], du[4];
    #pragma unroll
    for (int nf = 0; nf < 4; ++nf) {           // all operands in registers
      dg[nf] = __builtin_amdgcn_mfma_f32_16x16x32_bf16(afg, p.bg[nf], (v4f){0.f,0.f,0.f,0.f}, 0, 0, 0);
      du[nf] = __builtin_amdgcn_mfma_f32_16x16x32_bf16(afu, p.bu[nf], (v4f){0.f,0.f,0.f,0.f}, 0, 0, 0);
    }
    #pragma unroll
    for (int nf = 0; nf < 4; ++nf) {
      #pragma unroll
      for (int j = 0; j < 4; ++j) {
        int rj = (lane>>4)*4 + j;
        int fi = nf*16 + (lane&15);
        float cgv = b2f(cgw[rj*CT_LD + fi]);
        float cuv = b2f(cuw[rj*CT_LD + fi]);
        float gv = cgv + 2.f * dg[nf][j];
        float uv = cuv + 2.f * du[nf][j];
        float a  = gv * __builtin_amdgcn_rcpf(1.f + __expf(-gv)) * uv;   // silu(g)*u
        aww[rj*AW_LD + fi] = f2b(wR[j] * a);
      }
    }
    { // coalesced global store of weighted act from aww (2 x v8s per lane)
      int st = sTok[srj], ss = sSlot[srj];
      u16* dst = (ss ? actw1 : actw0) + (size_t)st*FD + f0 + sc;
      *(v8s*)dst       = *(const v8s*)(aww + srj*AW_LD + sc);
      *(v8s*)(dst + 8) = *(const v8s*)(aww + srj*AW_LD + sc + 8);
    }
    #pragma unroll
    for (int ks = 0; ks < 2; ++ks) {   // dA accumulate: [16 tok] x [16 r] over K=64
      v8s aA = *(const v8s*)(aww + (lane&15)*AW_LD + ks*32 + khalf*8);
      accDA = __builtin_amdgcn_mfma_f32_16x16x32_bf16(aA, p.ad[ks], accDA, 0, 0, 0);
    }
  };

  // 4 chunks/wave, 2-state register pipeline (named sets, static indexing)
  const int ch0 = fb*16 + w;
  PF pA, pB;
  LOADPF(ch0,      pA);
  LOADPF(ch0 + 4,  pB);
  COMPUTE(ch0,     pA);
  LOADPF(ch0 + 8,  pA);
  COMPUTE(ch0 + 4, pB);
  LOADPF(ch0 + 12, pB);
  COMPUTE(ch0 + 8, pA);
  COMPUTE(ch0 + 12, pB);

  #pragma unroll
  for (int j = 0; j < 4; ++j)
    dAred[w][((lane>>4)*4 + j)*16 + (lane&15)] = accDA[j];
  __syncthreads();
  {
    int row = tid >> 4, col = tid & 15;
    float s2 = dAred[0][row*16+col] + dAred[1][row*16+col] + dAred[2][row*16+col] + dAred[3][row*16+col];
    atomicAdd(&cC[((size_t)sTok[row]*2 + sSlot[row])*16 + col], 2.f * s2);
  }
}

// ---------- combine: abx[t] = [actw0+actw1 (bf16), scattered c coefs, zeros] ----------
__global__ __launch_bounds__(256)
void combine2_kernel(const u16* __restrict__ a0, const u16* __restrict__ a1,
                     const float* __restrict__ cC, const int* __restrict__ sel,
                     u16* __restrict__ abx) {
  int t = blockIdx.x, tid = threadIdx.x;
  const u16* p0 = a0 + (size_t)t * FD;
  const u16* p1 = a1 + (size_t)t * FD;
  u16* po = abx + (size_t)t * KXD;
  for (int i = tid * 8; i < FD; i += 256 * 8) {
    v8s x = *(const v8s*)(p0 + i);
    v8s y = *(const v8s*)(p1 + i);
    v8s o;
    #pragma unroll
    for (int j = 0; j < 8; ++j) o[j] = (short)f2b(b2f((u16)x[j]) + b2f((u16)y[j]));
    *(v8s*)(po + i) = o;
  }
  for (int c = tid; c < 512; c += 256) {  // ext cols; c>=128 zeroed
    float v = 0.f;
    if (c < 128) {
      int e_i = c >> 4, r = c & 15;
      if (sel[2*t]     == e_i) v += cC[((size_t)t*2 + 0)*16 + r];
      if (sel[2*t + 1] == e_i) v += cC[((size_t)t*2 + 1)*16 + r];
    }
    po[FD + c] = f2b(v);
  }
}

// ---------- launch ----------
extern "C" void kernel_launch(void* const* d_in, const int* in_sizes, int n_in,
                              void* d_out, int out_size, void* d_ws, size_t ws_size,
                              hipStream_t stream) {
  (void)in_sizes; (void)n_in; (void)out_size; (void)ws_size;
  const float* h  = (const float*)d_in[0];
  const float* gw = (const float*)d_in[1];
  const float* Wg = (const float*)d_in[2];
  const float* Wu = (const float*)d_in[3];
  const float* Wd = (const float*)d_in[4];
  const float* Ag = (const float*)d_in[5];
  const float* Bg = (const float*)d_in[6];
  const float* Au = (const float*)d_in[7];
  const float* Bu = (const float*)d_in[8];
  const float* Ad = (const float*)d_in[9];
  const float* Bd = (const float*)d_in[10];

  char* ws = (char*)d_ws;
  size_t off = 0;
  auto alloc = [&](size_t bytes) { size_t c = off; off += (bytes + 255) & ~(size_t)255; return c; };
  u16*  hb     = (u16*)(ws + alloc((size_t)TT*HD*2));             // 8 MB
  u16*  Bgux   = (u16*)(ws + alloc((size_t)(TT+1)*FD*2*2));       // 67.2 MB [Wg|Wu]; actw0/1; down partials
  u16*  Agu    = (u16*)(ws + alloc((size_t)256*HD*2));            // 1 MB [Ag all|Au all]
  u16*  Wdx    = (u16*)(ws + alloc((size_t)HD*KXD*2));            // 35.7 MB [HD][KXD]
  u16*  CGU    = (u16*)(ws + alloc((size_t)TT*NXE*2));            // 64 MB [TT][NXE]; later abx [TT][KXD]
  u16*  Bgb    = (u16*)(ws + alloc((size_t)NE*FD*16*2));          // 2 MB bf16
  u16*  Bub    = (u16*)(ws + alloc((size_t)NE*FD*16*2));          // 2 MB
  u16*  Adb    = (u16*)(ws + alloc((size_t)NE*16*FD*2));          // 2 MB
  float* hAx   = (float*)(ws + alloc((size_t)TT*256*4));          // 2 MB
  float* cC    = (float*)(ws + alloc((size_t)(TT+1)*2*16*4));
  int*  sel    = (int*)(ws + alloc((size_t)TT*2*4));
  int*  count  = (int*)(ws + alloc(256));
  int*  listTok= (int*)(ws + alloc((size_t)NE*TT*4));
  float* listW = (float*)(ws + alloc((size_t)NE*TT*4));
  u16*  actw0  = Bgux;                                  // alias: Bgux dead after gate/up GEMMs
  u16*  actw1  = Bgux + (size_t)(TT+1)*FD;
  u16*  abx    = CGU;                                   // alias: CGU dead after expert_kernel
  float* parts = (float*)Bgux;                          // alias: actw dead after combine2 (64 MB <= 67.2)

  hipMemsetAsync(count, 0, NE*sizeof(int), stream);
  hipMemsetAsync(cC, 0, (size_t)(TT+1)*2*16*4, stream);

  // one mega-prep: all casts + Bd-ext + hAx zero
  prep_kernel<<<PREP_BLOCKS, 256, 0, stream>>>(h, Wg, Wu, Wd, Ag, Au, Bg, Bu, Ad, Bd,
                                               hb, Bgux, Agu, Wdx, Bgb, Bub, Adb, hAx);

  router_kernel<<<TT, 64, 0, stream>>>(h, gw, sel, count, listTok, listW);

  // hAx = h @ [Ag;Au]^T  (M=2048, N=256, K=2048, split-K=8 -> 256 blocks)
  gemm128a<<<dim3(16, 2, 8), 256, 0, stream>>>(hb, Agu, hAx, HD, 256);

  // gate: CG = h @ Wg^T   (M=2048, N=8192, K=2048) -> 256 blocks = 1 exact round
  gemm256<0><<<dim3(8, 32, 1), 512, 0, stream>>>(hb, Bgux, CGU, HD, HD, NXE);
  // up:   CU = h @ Wu^T   -> 256 blocks = 1 exact round (writes CGU cols FD..)
  gemm256<0><<<dim3(8, 32, 1), 512, 0, stream>>>(hb, Bgux + (size_t)FD*HD, CGU + CU_OFF, HD, HD, NXE);

  // per-expert: deltas, act, weighted act into slot buffers (aliasing Bgux), c coefs
  expert_kernel<<<dim3(128, NE, 8), 256, 0, stream>>>(CGU, hAx, Bgb, Bub, Adb, count, listTok, listW,
                                                      actw0, actw1, cC);

  // abx = [actw0+actw1, c-scatter, zeros]  (writes into the dead CGU region)
  combine2_kernel<<<TT, 256, 0, stream>>>(actw0, actw1, cC, sel, abx);

  // partials[z] = abx @ Wdx^T slice z  (M=2048, N=2048, K=8704, split-K=4 -> 256 blocks, no atomics)
  gemm256<3><<<dim3(8, 8, 4), 512, 0, stream>>>(abx, Wdx, parts, KXD, KXD/4, HD);

  // out = sum of 4 partials
  reduce4_kernel<<<4096, 256, 0, stream>>>(parts, (float*)d_out);
}

// Round 11
// 436.619 us; speedup vs baseline: 1.0444x; 1.0392x over previous
//
#include <hip/hip_runtime.h>
#include <hip/hip_bf16.h>

typedef __attribute__((ext_vector_type(8))) short v8s;   // 8 x bf16 (as i16)
typedef __attribute__((ext_vector_type(4))) float v4f;
typedef unsigned short u16;

static constexpr int TT = 2048;        // tokens
static constexpr int HD = 2048;        // hidden
static constexpr int FD = 8192;        // ffn dim
static constexpr int NE = 8;           // experts
static constexpr int NR = 16;          // lora rank
static constexpr int NXE = 2*FD;       // 16384: merged [Wg | Wu] cols
static constexpr int CU_OFF = FD;      // up offset inside CGU row
static constexpr int KXD = FD + 512;   // 8704 = 136*64 ext K for down GEMM (34*64*4)

// ---------- helpers ----------
__device__ __forceinline__ u16 f2b(float f) {            // fp32 -> bf16 RNE
  union { float f; unsigned u; } v; v.f = f;
  unsigned r = v.u + 0x7FFFu + ((v.u >> 16) & 1u);
  return (u16)(r >> 16);
}
__device__ __forceinline__ float b2f(u16 h) {
  union { unsigned u; float f; } v; v.u = ((unsigned)h) << 16;
  return v.f;
}
__device__ __forceinline__ v8s pack8(v4f a, v4f b) {
  v8s r;
  r[0]=(short)f2b(a.x); r[1]=(short)f2b(a.y); r[2]=(short)f2b(a.z); r[3]=(short)f2b(a.w);
  r[4]=(short)f2b(b.x); r[5]=(short)f2b(b.y); r[6]=(short)f2b(b.z); r[7]=(short)f2b(b.w);
  return r;
}
__device__ __forceinline__ void gload_lds16(const void* g, void* l) {
  __builtin_amdgcn_global_load_lds(
      (const __attribute__((address_space(1))) unsigned int*)g,
      (__attribute__((address_space(3))) unsigned int*)l, 16, 0, 0);
}
__device__ __forceinline__ void barrier_pin() {
  __builtin_amdgcn_s_barrier();
  __builtin_amdgcn_sched_barrier(0);
}
__device__ __forceinline__ void vm_wait4() { asm volatile("s_waitcnt vmcnt(4)" ::: "memory"); }
__device__ __forceinline__ void vm_wait0() { asm volatile("s_waitcnt vmcnt(0)" ::: "memory"); }

template<int Q>
__device__ __forceinline__ void mmq(v4f (&acc)[8][4], const v8s (&af)[2][2], const v8s (&bf)[4][2]) {
  __builtin_amdgcn_s_setprio(1);
  #pragma unroll
  for (int m2 = 0; m2 < 2; ++m2)
    #pragma unroll
    for (int nf = 0; nf < 4; ++nf) {
      acc[Q*2+m2][nf] = __builtin_amdgcn_mfma_f32_16x16x32_bf16(af[m2][0], bf[nf][0], acc[Q*2+m2][nf], 0, 0, 0);
      acc[Q*2+m2][nf] = __builtin_amdgcn_mfma_f32_16x16x32_bf16(af[m2][1], bf[nf][1], acc[Q*2+m2][nf], 0, 0, 0);
    }
  __builtin_amdgcn_s_setprio(0);
}

// ---------- mega prep v4: v2 shape (16 fp32/thread), grid-stride, router fused ----------
// virtual blocks (4096 elems each unless noted):
//  [0,1024) h->hb  [1024,5120) Wg  [5120,9216) Wu  [9216,13312) Wd->Wdx(ld, NT)
//  [13312,13376) Ag  [13376,13440) Au  [13440,13696) Bg  [13696,13952) Bu
//  [13952,14208) Ad  [14208,14464) Bd->Wdx ext (NT)  [14464,14592) zero hAx
//  [14592,15104) router (4 tokens/vb)
static constexpr int PREP_VB = 15104;
static constexpr int PREP_BLOCKS = 7552;   // x2 grid-stride
__global__ __launch_bounds__(256)
void prep_kernel(const float* __restrict__ h, const float* __restrict__ Wg,
                 const float* __restrict__ Wu, const float* __restrict__ Wd,
                 const float* __restrict__ Ag, const float* __restrict__ Au,
                 const float* __restrict__ Bg, const float* __restrict__ Bu,
                 const float* __restrict__ Ad, const float* __restrict__ Bd,
                 const float* __restrict__ gw,
                 u16* __restrict__ hb, u16* __restrict__ Bgux, u16* __restrict__ Agu,
                 u16* __restrict__ Wdx, u16* __restrict__ Bgb, u16* __restrict__ Bub,
                 u16* __restrict__ Adb, float* __restrict__ hAx,
                 int* __restrict__ sel, int* __restrict__ count,
                 int* __restrict__ listTok, float* __restrict__ listW) {
  const int tid = threadIdx.x;
  for (int vb = blockIdx.x; vb < PREP_VB; vb += PREP_BLOCKS) {
    const int b = vb;
    auto cast16 = [&](const float* s, u16* d, long blk) {
      long i = blk*4096 + (long)tid*16;
      v4f a0 = *(const v4f*)(s+i),    a1 = *(const v4f*)(s+i+4);
      v4f a2 = *(const v4f*)(s+i+8),  a3 = *(const v4f*)(s+i+12);
      *(v8s*)(d+i)   = pack8(a0, a1);
      *(v8s*)(d+i+8) = pack8(a2, a3);
    };
    if (b < 1024) { cast16(h, hb, b); }
    else if (b < 5120)  { cast16(Wg, Bgux, b-1024); }
    else if (b < 9216)  { cast16(Wu, Bgux + (size_t)FD*HD, b-5120); }
    else if (b < 13312) {
      long idx = (long)(b-9216)*4096 + (long)tid*16;   // over [HD][FD]
      long r = idx >> 13; int c = (int)(idx & 8191);
      const float* s = Wd + r*FD + c;
      u16* d = Wdx + r*KXD + c;
      v4f a0 = *(const v4f*)s,     a1 = *(const v4f*)(s+4);
      v4f a2 = *(const v4f*)(s+8), a3 = *(const v4f*)(s+12);
      __builtin_nontemporal_store(pack8(a0, a1), (v8s*)d);
      __builtin_nontemporal_store(pack8(a2, a3), (v8s*)(d+8));
    }
    else if (b < 13376) { cast16(Ag, Agu, b-13312); }
    else if (b < 13440) { cast16(Au, Agu + (size_t)128*HD, b-13376); }
    else if (b < 13696) { cast16(Bg, Bgb, b-13440); }
    else if (b < 13952) { cast16(Bu, Bub, b-13696); }
    else if (b < 14208) { cast16(Ad, Adb, b-13952); }
    else if (b < 14464) {
      long idx = (long)(b-14208)*4096 + (long)tid*16;  // over [HD][512] ext cols
      int hrow = (int)(idx >> 9); int c = (int)(idx & 511);
      u16* d = Wdx + (size_t)hrow*KXD + FD + c;
      if (c < 128) {            // one full (e, r0..15) row per 16-chunk
        const float* s = Bd + ((size_t)(c>>4)*HD + hrow)*16;
        v4f a0 = *(const v4f*)s,     a1 = *(const v4f*)(s+4);
        v4f a2 = *(const v4f*)(s+8), a3 = *(const v4f*)(s+12);
        __builtin_nontemporal_store(pack8(a0, a1), (v8s*)d);
        __builtin_nontemporal_store(pack8(a2, a3), (v8s*)(d+8));
      } else {
        v8s z = {0,0,0,0,0,0,0,0};
        __builtin_nontemporal_store(z, (v8s*)d);
        __builtin_nontemporal_store(z, (v8s*)(d+8));
      }
    }
    else if (b < 14592) {
      long i = (long)(b-14464)*4096 + (long)tid*16;
      v4f z = {0.f,0.f,0.f,0.f};
      *(v4f*)(hAx+i) = z; *(v4f*)(hAx+i+4) = z;
      *(v4f*)(hAx+i+8) = z; *(v4f*)(hAx+i+12) = z;
    }
    else {   // router: one token per wave
      int t = (b - 14592)*4 + (tid >> 6);
      int lane = tid & 63;
      const float* hp = h + (size_t)t * HD;
      float acc[8] = {0,0,0,0,0,0,0,0};
      for (int i = lane; i < HD; i += 64) {
        float hv = hp[i];
        #pragma unroll
        for (int e = 0; e < 8; ++e) acc[e] += hv * gw[e*HD + i];
      }
      #pragma unroll
      for (int off = 32; off > 0; off >>= 1) {
        #pragma unroll
        for (int e = 0; e < 8; ++e) acc[e] += __shfl_xor(acc[e], off, 64);
      }
      if (lane == 0) {
        int e0 = -1, e1 = -1; float b0 = -1e30f, b1 = -1e30f;
        #pragma unroll
        for (int e = 0; e < 8; ++e) {
          float v = acc[e];
          if (v > b0) { b1 = b0; e1 = e0; b0 = v; e0 = e; }
          else if (v > b1) { b1 = v; e1 = e; }
        }
        float p1 = __expf(b1 - b0);            // p0 = 1
        float w0 = 1.f / (1.f + p1);
        float w1 = p1 * w0;
        sel[2*t] = e0; sel[2*t+1] = e1;
        int pos0 = atomicAdd(&count[e0], 1);
        listTok[e0*TT + pos0] = t;           listW[e0*TT + pos0] = w0;
        int pos1 = atomicAdd(&count[e1], 1);
        listTok[e1*TT + pos1] = t | (1<<20); listW[e1*TT + pos1] = w1;
      }
    }
  }
}

// ---------- 128x128x64 bf16 GEMM (m97 structure), C = A @ B^T, split-K atomic ----------
__global__ __launch_bounds__(256)
void gemm128a(const u16* __restrict__ A, const u16* __restrict__ B, float* __restrict__ Cout,
              int K, int ldc) {
  __shared__ u16 As[128*64];
  __shared__ u16 Bs[128*64];
  const int tid  = threadIdx.x;
  const int lane = tid & 63, wid = tid >> 6;
  const int gx = gridDim.x;
  const int lin = blockIdx.y * gx + blockIdx.x;
  const int chunk = (gx * gridDim.y) >> 3;
  const int wg = (lin & 7) * chunk + (lin >> 3);
  const int m0 = (wg % gx) * 128, n0 = (wg / gx) * 128;
  const int kc = K / gridDim.z;
  const int kbeg = blockIdx.z * kc;
  const int wr = wid >> 1, wc = wid & 1;
  const int lrow = lane >> 3, lcol = (lane & 7) * 8;
  v4f acc[4][4];
  #pragma unroll
  for (int mi = 0; mi < 4; ++mi)
    #pragma unroll
    for (int ni = 0; ni < 4; ++ni) acc[mi][ni] = (v4f){0.f,0.f,0.f,0.f};

  for (int k0 = kbeg; k0 < kbeg + kc; k0 += 64) {
    #pragma unroll
    for (int it = 0; it < 4; ++it) {
      int seg = wid*4 + it;
      int row = seg*8 + lrow;
      gload_lds16(A + (size_t)(m0+row)*K + k0 + lcol, As + seg*512);
      gload_lds16(B + (size_t)(n0+row)*K + k0 + lcol, Bs + seg*512);
    }
    __syncthreads();
    #pragma unroll
    for (int kk = 0; kk < 64; kk += 32) {
      v8s af[4], bfr[4];
      #pragma unroll
      for (int mi = 0; mi < 4; ++mi)
        af[mi] = *(const v8s*)(As + (wr*64 + mi*16 + (lane&15))*64 + kk + (lane>>4)*8);
      #pragma unroll
      for (int ni = 0; ni < 4; ++ni)
        bfr[ni] = *(const v8s*)(Bs + (wc*64 + ni*16 + (lane&15))*64 + kk + (lane>>4)*8);
      #pragma unroll
      for (int mi = 0; mi < 4; ++mi)
        #pragma unroll
        for (int ni = 0; ni < 4; ++ni)
          acc[mi][ni] = __builtin_amdgcn_mfma_f32_16x16x32_bf16(af[mi], bfr[ni], acc[mi][ni], 0, 0, 0);
    }
    __syncthreads();
  }

  #pragma unroll
  for (int mi = 0; mi < 4; ++mi)
    #pragma unroll
    for (int j = 0; j < 4; ++j) {
      int row = m0 + wr*64 + mi*16 + (lane>>4)*4 + j;
      size_t base = (size_t)row*ldc + n0 + wc*64 + (lane&15);
      #pragma unroll
      for (int ni = 0; ni < 4; ++ni)
        atomicAdd(&Cout[base + ni*16], acc[mi][ni][j]);
    }
}

// ---------- 256x256 8-phase bf16 GEMM, C = A @ B^T  (T1+T2+T3+T4+T5) ----------
// MODE 0: bf16 store. MODE 3: fp32 per-z-slice partial store (no atomics).
template<int MODE>
__global__ __launch_bounds__(512, 2)
void gemm256(const u16* __restrict__ A, const u16* __restrict__ B, void* __restrict__ Cout,
             int ldk, int kchunk, int ldc) {
  __shared__ u16 lds[2][2][2][8192];
  const int tid = threadIdx.x, lane = tid & 63, wid = tid >> 6;
  const int gx = gridDim.x;
  const int nwg = gx * gridDim.y;
  const int lin = blockIdx.y * gx + blockIdx.x;
  const int chunk = nwg >> 3;                       // nwg % 8 == 0 by construction
  const int wg = (lin & 7) * chunk + (lin >> 3);    // bijective XCD swizzle
  const int m0 = (wg % gx) * 256, n0 = (wg / gx) * 256;
  const long kbeg = (long)blockIdx.z * kchunk;
  const int NK = kchunk >> 6, NI = NK >> 1;         // NK even
  const int wr = wid >> 2, wc = wid & 3;

  const int s_r = (wid << 4) + (lane >> 3);
  const int s_c = lane & 7;

  auto STAGE = [&](int slot, int ab, int half, const u16* M, int rc0, int kt) {
    const u16* g0 = M + (size_t)(rc0 + half*128 + s_r) * ldk + kbeg + kt*64 + ((s_c ^ (s_r & 7)) << 3);
    gload_lds16(g0, &lds[slot][ab][half][wid << 10]);
    const int r1 = s_r + 8;
    const u16* g1 = M + (size_t)(rc0 + half*128 + r1) * ldk + kbeg + kt*64 + ((s_c ^ (r1 & 7)) << 3);
    gload_lds16(g1, &lds[slot][ab][half][(wid << 10) + 512]);
  };
  auto LDA = [&](int slot, int mf, int c16b) -> v8s {
    int rr = (mf << 4) + (lane & 15);
    return *(const v8s*)&lds[slot][0][wr][rr*64 + (((c16b + (lane >> 4)) ^ (rr & 7)) << 3)];
  };
  auto LDB = [&](int slot, int nf, int c16b) -> v8s {
    int row = (wc << 6) + (nf << 4) + (lane & 15);
    int rr = row & 127;
    return *(const v8s*)&lds[slot][1][row >> 7][rr*64 + (((c16b + (lane >> 4)) ^ (rr & 7)) << 3)];
  };

  v4f acc[8][4];
  #pragma unroll
  for (int mf = 0; mf < 8; ++mf)
    #pragma unroll
    for (int nf = 0; nf < 4; ++nf) acc[mf][nf] = (v4f){0.f,0.f,0.f,0.f};

  STAGE(0,1,0,B,n0,0); STAGE(0,1,1,B,n0,0);
  STAGE(0,0,0,A,m0,0); STAGE(0,0,1,A,m0,0);
  STAGE(1,1,0,B,n0,1); STAGE(1,1,1,B,n0,1);
  vm_wait4();
  barrier_pin();

  for (int i = 0; i < NI; ++i) {
    const int kt0 = 2*i, kt1 = kt0 + 1;
    const int kt2c = (kt0 + 2 < NK) ? kt0 + 2 : kt0;
    const bool s45 = (kt0 + 2 < NK), s67 = (kt1 + 2 < NK);
    v8s bf[4][2], af[2][2];
    // ---- phase 0 (slot0, q0)
    #pragma unroll
    for (int nf = 0; nf < 4; ++nf) { bf[nf][0] = LDB(0,nf,0); bf[nf][1] = LDB(0,nf,4); }
    af[0][0]=LDA(0,0,0); af[0][1]=LDA(0,0,4); af[1][0]=LDA(0,1,0); af[1][1]=LDA(0,1,4);
    STAGE(1,0,0,A,m0,kt1);
    barrier_pin(); mmq<0>(acc,af,bf); barrier_pin();
    // ---- phase 1 (slot0, q1)
    af[0][0]=LDA(0,2,0); af[0][1]=LDA(0,2,4); af[1][0]=LDA(0,3,0); af[1][1]=LDA(0,3,4);
    STAGE(1,0,1,A,m0,kt1);
    barrier_pin(); mmq<1>(acc,af,bf); barrier_pin();
    // ---- phase 2 (slot0, q2)
    af[0][0]=LDA(0,4,0); af[0][1]=LDA(0,4,4); af[1][0]=LDA(0,5,0); af[1][1]=LDA(0,5,4);
    STAGE(0,1,0,B,n0,kt2c);
    barrier_pin(); mmq<2>(acc,af,bf); barrier_pin();
    // ---- phase 3 (slot0, q3)
    af[0][0]=LDA(0,6,0); af[0][1]=LDA(0,6,4); af[1][0]=LDA(0,7,0); af[1][1]=LDA(0,7,4);
    STAGE(0,1,1,B,n0,kt2c);
    vm_wait4();
    barrier_pin(); mmq<3>(acc,af,bf); barrier_pin();
    // ---- phase 4 (slot1, q0)
    #pragma unroll
    for (int nf = 0; nf < 4; ++nf) { bf[nf][0] = LDB(1,nf,0); bf[nf][1] = LDB(1,nf,4); }
    af[0][0]=LDA(1,0,0); af[0][1]=LDA(1,0,4); af[1][0]=LDA(1,1,0); af[1][1]=LDA(1,1,4);
    if (s45) STAGE(0,0,0,A,m0,kt0+2);
    barrier_pin(); mmq<0>(acc,af,bf); barrier_pin();
    // ---- phase 5 (slot1, q1)
    af[0][0]=LDA(1,2,0); af[0][1]=LDA(1,2,4); af[1][0]=LDA(1,3,0); af[1][1]=LDA(1,3,4);
    if (s45) STAGE(0,0,1,A,m0,kt0+2);
    barrier_pin(); mmq<1>(acc,af,bf); barrier_pin();
    // ---- phase 6 (slot1, q2)
    af[0][0]=LDA(1,4,0); af[0][1]=LDA(1,4,4); af[1][0]=LDA(1,5,0); af[1][1]=LDA(1,5,4);
    if (s67) STAGE(1,1,0,B,n0,kt1+2);
    barrier_pin(); mmq<2>(acc,af,bf); barrier_pin();
    // ---- phase 7 (slot1, q3)
    af[0][0]=LDA(1,6,0); af[0][1]=LDA(1,6,4); af[1][0]=LDA(1,7,0); af[1][1]=LDA(1,7,4);
    if (s67) STAGE(1,1,1,B,n0,kt1+2);
    vm_wait4();
    barrier_pin(); mmq<3>(acc,af,bf); barrier_pin();
  }
  vm_wait0();

  if (MODE == 0) {
    u16* C = (u16*)Cout;
    #pragma unroll
    for (int mf = 0; mf < 8; ++mf)
      #pragma unroll
      for (int j = 0; j < 4; ++j) {
        int row = m0 + wr*128 + mf*16 + (lane>>4)*4 + j;
        size_t base = (size_t)row*ldc + n0 + wc*64 + (lane&15);
        #pragma unroll
        for (int nf = 0; nf < 4; ++nf)
          C[base + nf*16] = f2b(acc[mf][nf][j]);
      }
  } else {
    float* C = (float*)Cout + (size_t)blockIdx.z * TT * HD;   // per-slice partial
    #pragma unroll
    for (int mf = 0; mf < 8; ++mf)
      #pragma unroll
      for (int j = 0; j < 4; ++j) {
        int row = m0 + wr*128 + mf*16 + (lane>>4)*4 + j;
        size_t base = (size_t)row*ldc + n0 + wc*64 + (lane&15);
        #pragma unroll
        for (int nf = 0; nf < 4; ++nf)
          C[base + nf*16] = acc[mf][nf][j];
      }
  }
}

// ---------- reduce: out = sum of 4 fp32 partials ----------
__global__ __launch_bounds__(256)
void reduce4_kernel(const float* __restrict__ P, float* __restrict__ out) {
  long i = ((long)blockIdx.x * 256 + threadIdx.x) * 4;
  const size_t S = (size_t)TT * HD;
  v4f s = *(const v4f*)(P + i);
  s = s + *(const v4f*)(P + S + i);
  s = s + *(const v4f*)(P + 2*S + i);
  s = s + *(const v4f*)(P + 3*S + i);
  *(v4f*)(out + i) = s;
}

// ---------- expert kernel v3: register double-buffer for ALL MFMA operands ----------
// grid (128 groups, NE, 8 f-blocks). Per block: 16 tokens x 1024 f-cols.
static constexpr int HA_LD = 40;
static constexpr int AW_LD = 72;
static constexpr int CT_LD = 72;

struct PF {      // per-chunk prefetch state
  v8s bg[4], bu[4], ad[2];
  v8s rg0, ru0, rg1, ru1;
};

__global__ __launch_bounds__(256)
void expert_kernel(const u16* __restrict__ CGU,                                // [TT][NXE]
                   const float* __restrict__ hAx,                              // [TT][256] fp32
                   const u16* __restrict__ Bgb, const u16* __restrict__ Bub,   // [E][F][16] bf16
                   const u16* __restrict__ Adb,                                // [E][16][F] bf16
                   const int* __restrict__ count, const int* __restrict__ listTok,
                   const float* __restrict__ listW,
                   u16* __restrict__ actw0, u16* __restrict__ actw1,           // [TT+1][F]
                   float* __restrict__ cC) {                                   // [TT+1][2][16]
  const int e = blockIdx.y, g = blockIdx.x, fb = blockIdx.z;
  const int n = count[e];
  if (g*16 >= n) return;
  const int tid = threadIdx.x, lane = tid & 63, w = tid >> 6;
  __shared__ u16 hAg[16*HA_LD], hAu[16*HA_LD];
  __shared__ u16 AWs[4][16*AW_LD];
  __shared__ u16 cgT[4][16*CT_LD], cuT[4][16*CT_LD];
  __shared__ int sTok[16], sSlot[16];
  __shared__ float sW[16];
  __shared__ float dAred[4][256];

  if (tid < 16) {
    int idx = g*16 + tid;
    if (idx < n) {
      int ent = listTok[e*TT + idx];
      sTok[tid] = ent & 0xFFFF; sSlot[tid] = (ent >> 20) & 1; sW[tid] = listW[e*TT + idx];
    } else { sTok[tid] = TT; sSlot[tid] = 0; sW[tid] = 0.f; }
  }
  __syncthreads();
  if (tid < 128) {   // stage hA (both tensors) from hAx fp32, zero-pad K 16..31
    int tensor = tid >> 6;
    int sub = tid & 63;
    int row = sub >> 2, c8 = (sub & 3) * 8;
    int trd = min(sTok[row], TT - 1);
    u16 vals[8];
    if (c8 < 16) {
      const float* src = hAx + (size_t)trd*256 + tensor*128 + e*NR + c8;
      v4f a = *(const v4f*)src, b = *(const v4f*)(src + 4);
      v8s p = pack8(a, b);
      #pragma unroll
      for (int q = 0; q < 8; ++q) vals[q] = (u16)p[q];
    } else {
      #pragma unroll
      for (int q = 0; q < 8; ++q) vals[q] = 0;
    }
    u16* dst = (tensor ? hAu : hAg) + row*HA_LD + c8;
    #pragma unroll
    for (int q = 0; q < 8; ++q) dst[q] = vals[q];
  }
  __syncthreads();

  int tR[4], slR[4]; float wR[4];
  #pragma unroll
  for (int j = 0; j < 4; ++j) {
    int r = (lane>>4)*4 + j;
    tR[j] = sTok[r]; slR[j] = sSlot[r]; wR[j] = sW[r];
  }
  const int khalf = lane >> 4;
  v8s afg = *(const v8s*)(hAg + (lane&15)*HA_LD + khalf*8);
  v8s afu = *(const v8s*)(hAu + (lane&15)*HA_LD + khalf*8);
  v4f accDA = (v4f){0.f,0.f,0.f,0.f};
  u16* aww = AWs[w]; u16* cgw = cgT[w]; u16* cuw = cuT[w];
  const v8s zero8 = {0,0,0,0,0,0,0,0};
  const u16* BgE = Bgb + (size_t)e*FD*16;
  const u16* BuE = Bub + (size_t)e*FD*16;
  const u16* AdE = Adb + (size_t)e*16*FD;

  const int srj = lane >> 2, sc = (lane & 3) * 16;
  const int srow = lane >> 3, c8s = (lane & 7) * 8;
  const size_t trdA = (size_t)min(sTok[srow], TT - 1);
  const size_t trdB = (size_t)min(sTok[srow + 8], TT - 1);

  auto LOADPF = [&](int ch, PF& p) {
    const int f0 = ch * 64;
    #pragma unroll
    for (int nf = 0; nf < 4; ++nf) {
      int f = f0 + nf*16 + (lane & 15);
      p.bg[nf] = (khalf < 2) ? *(const v8s*)(BgE + (size_t)f*16 + khalf*8) : zero8;
      p.bu[nf] = (khalf < 2) ? *(const v8s*)(BuE + (size_t)f*16 + khalf*8) : zero8;
    }
    #pragma unroll
    for (int ks = 0; ks < 2; ++ks)
      p.ad[ks] = *(const v8s*)(AdE + (size_t)(lane&15)*FD + f0 + ks*32 + khalf*8);
    p.rg0 = *(const v8s*)(CGU + trdA*NXE + f0 + c8s);
    p.ru0 = *(const v8s*)(CGU + trdA*NXE + CU_OFF + f0 + c8s);
    p.rg1 = *(const v8s*)(CGU + trdB*NXE + f0 + c8s);
    p.ru1 = *(const v8s*)(CGU + trdB*NXE + CU_OFF + f0 + c8s);
  };

  auto COMPUTE = [&](int ch, const PF& p) {
    const int f0 = ch * 64;
    *(v8s*)(cgw + srow*CT_LD + c8s)     = p.rg0;
    *(v8s*)(cgw + (srow+8)*CT_LD + c8s) = p.rg1;
    *(v8s*)(cuw + srow*CT_LD + c8s)     = p.ru0;
    *(v8s*)(cuw + (srow+8)*CT_LD + c8s) = p.ru1;
    v4f dg[4], du[4];
    #pragma unroll
    for (int nf = 0; nf < 4; ++nf) {
      dg[nf] = __builtin_amdgcn_mfma_f32_16x16x32_bf16(afg, p.bg[nf], (v4f){0.f,0.f,0.f,0.f}, 0, 0, 0);
      du[nf] = __builtin_amdgcn_mfma_f32_16x16x32_bf16(afu, p.bu[nf], (v4f){0.f,0.f,0.f,0.f}, 0, 0, 0);
    }
    #pragma unroll
    for (int nf = 0; nf < 4; ++nf) {
      #pragma unroll
      for (int j = 0; j < 4; ++j) {
        int rj = (lane>>4)*4 + j;
        int fi = nf*16 + (lane&15);
        float cgv = b2f(cgw[rj*CT_LD + fi]);
        float cuv = b2f(cuw[rj*CT_LD + fi]);
        float gv = cgv + 2.f * dg[nf][j];
        float uv = cuv + 2.f * du[nf][j];
        float a  = gv * __builtin_amdgcn_rcpf(1.f + __expf(-gv)) * uv;   // silu(g)*u
        aww[rj*AW_LD + fi] = f2b(wR[j] * a);
      }
    }
    {
      int st = sTok[srj], ss = sSlot[srj];
      u16* dst = (ss ? actw1 : actw0) + (size_t)st*FD + f0 + sc;
      *(v8s*)dst       = *(const v8s*)(aww + srj*AW_LD + sc);
      *(v8s*)(dst + 8) = *(const v8s*)(aww + srj*AW_LD + sc + 8);
    }
    #pragma unroll
    for (int ks = 0; ks < 2; ++ks) {
      v8s aA = *(const v8s*)(aww + (lane&15)*AW_LD + ks*32 + khalf*8);
      accDA = __builtin_amdgcn_mfma_f32_16x16x32_bf16(aA, p.ad[ks], accDA, 0, 0, 0);
    }
  };

  const int ch0 = fb*16 + w;
  PF pA, pB;
  LOADPF(ch0,      pA);
  LOADPF(ch0 + 4,  pB);
  COMPUTE(ch0,     pA);
  LOADPF(ch0 + 8,  pA);
  COMPUTE(ch0 + 4, pB);
  LOADPF(ch0 + 12, pB);
  COMPUTE(ch0 + 8, pA);
  COMPUTE(ch0 + 12, pB);

  #pragma unroll
  for (int j = 0; j < 4; ++j)
    dAred[w][((lane>>4)*4 + j)*16 + (lane&15)] = accDA[j];
  __syncthreads();
  {
    int row = tid >> 4, col = tid & 15;
    float s2 = dAred[0][row*16+col] + dAred[1][row*16+col] + dAred[2][row*16+col] + dAred[3][row*16+col];
    atomicAdd(&cC[((size_t)sTok[row]*2 + sSlot[row])*16 + col], 2.f * s2);
  }
}

// ---------- combine: abx[t] = [actw0+actw1 (bf16), scattered c coefs, zeros] ----------
__global__ __launch_bounds__(256)
void combine2_kernel(const u16* __restrict__ a0, const u16* __restrict__ a1,
                     const float* __restrict__ cC, const int* __restrict__ sel,
                     u16* __restrict__ abx) {
  int t = blockIdx.x, tid = threadIdx.x;
  const u16* p0 = a0 + (size_t)t * FD;
  const u16* p1 = a1 + (size_t)t * FD;
  u16* po = abx + (size_t)t * KXD;
  for (int i = tid * 8; i < FD; i += 256 * 8) {
    v8s x = *(const v8s*)(p0 + i);
    v8s y = *(const v8s*)(p1 + i);
    v8s o;
    #pragma unroll
    for (int j = 0; j < 8; ++j) o[j] = (short)f2b(b2f((u16)x[j]) + b2f((u16)y[j]));
    *(v8s*)(po + i) = o;
  }
  for (int c = tid; c < 512; c += 256) {  // ext cols; c>=128 zeroed
    float v = 0.f;
    if (c < 128) {
      int e_i = c >> 4, r = c & 15;
      if (sel[2*t]     == e_i) v += cC[((size_t)t*2 + 0)*16 + r];
      if (sel[2*t + 1] == e_i) v += cC[((size_t)t*2 + 1)*16 + r];
    }
    po[FD + c] = f2b(v);
  }
}

// ---------- launch ----------
extern "C" void kernel_launch(void* const* d_in, const int* in_sizes, int n_in,
                              void* d_out, int out_size, void* d_ws, size_t ws_size,
                              hipStream_t stream) {
  (void)in_sizes; (void)n_in; (void)out_size; (void)ws_size;
  const float* h  = (const float*)d_in[0];
  const float* gw = (const float*)d_in[1];
  const float* Wg = (const float*)d_in[2];
  const float* Wu = (const float*)d_in[3];
  const float* Wd = (const float*)d_in[4];
  const float* Ag = (const float*)d_in[5];
  const float* Bg = (const float*)d_in[6];
  const float* Au = (const float*)d_in[7];
  const float* Bu = (const float*)d_in[8];
  const float* Ad = (const float*)d_in[9];
  const float* Bd = (const float*)d_in[10];

  char* ws = (char*)d_ws;
  size_t off = 0;
  auto alloc = [&](size_t bytes) { size_t c = off; off += (bytes + 255) & ~(size_t)255; return c; };
  u16*  hb     = (u16*)(ws + alloc((size_t)TT*HD*2));             // 8 MB
  u16*  Bgux   = (u16*)(ws + alloc((size_t)(TT+1)*FD*2*2));       // 67.2 MB [Wg|Wu]; actw0/1; down partials
  u16*  Agu    = (u16*)(ws + alloc((size_t)256*HD*2));            // 1 MB [Ag all|Au all]
  u16*  Wdx    = (u16*)(ws + alloc((size_t)HD*KXD*2));            // 35.7 MB [HD][KXD]
  u16*  CGU    = (u16*)(ws + alloc((size_t)TT*NXE*2));            // 64 MB [TT][NXE]; later abx [TT][KXD]
  u16*  Bgb    = (u16*)(ws + alloc((size_t)NE*FD*16*2));          // 2 MB bf16
  u16*  Bub    = (u16*)(ws + alloc((size_t)NE*FD*16*2));          // 2 MB
  u16*  Adb    = (u16*)(ws + alloc((size_t)NE*16*FD*2));          // 2 MB
  float* hAx   = (float*)(ws + alloc((size_t)TT*256*4));          // 2 MB
  size_t cC_bytes = ((size_t)(TT+1)*2*16*4 + 255) & ~(size_t)255;
  float* cC    = (float*)(ws + alloc((size_t)(TT+1)*2*16*4));     // adjacent to count
  int*  count  = (int*)(ws + alloc(256));
  int*  sel    = (int*)(ws + alloc((size_t)TT*2*4));
  int*  listTok= (int*)(ws + alloc((size_t)NE*TT*4));
  float* listW = (float*)(ws + alloc((size_t)NE*TT*4));
  u16*  actw0  = Bgux;                                  // alias: Bgux dead after gate/up GEMM
  u16*  actw1  = Bgux + (size_t)(TT+1)*FD;
  u16*  abx    = CGU;                                   // alias: CGU dead after expert_kernel
  float* parts = (float*)Bgux;                          // alias: actw dead after combine2 (64 MB <= 67.2)

  // single memset: cC (fp32 zeros) + count (adjacent)
  hipMemsetAsync(cC, 0, cC_bytes + 256, stream);

  // mega-prep: all casts + Bd-ext + hAx zero + router
  prep_kernel<<<PREP_BLOCKS, 256, 0, stream>>>(h, Wg, Wu, Wd, Ag, Au, Bg, Bu, Ad, Bd, gw,
                                               hb, Bgux, Agu, Wdx, Bgb, Bub, Adb, hAx,
                                               sel, count, listTok, listW);

  // hAx = h @ [Ag;Au]^T  (M=2048, N=256, K=2048, split-K=8 -> 256 blocks)
  gemm128a<<<dim3(16, 2, 8), 256, 0, stream>>>(hb, Agu, hAx, HD, 256);

  // CGU = h @ [Wg|Wu]^T  (M=2048, N=16384, K=2048) -> 512 blocks = 2 exact rounds
  gemm256<0><<<dim3(8, 64, 1), 512, 0, stream>>>(hb, Bgux, CGU, HD, HD, NXE);

  // per-expert: deltas, act, weighted act into slot buffers (aliasing Bgux), c coefs
  expert_kernel<<<dim3(128, NE, 8), 256, 0, stream>>>(CGU, hAx, Bgb, Bub, Adb, count, listTok, listW,
                                                      actw0, actw1, cC);

  // abx = [actw0+actw1, c-scatter, zeros]  (writes into the dead CGU region)
  combine2_kernel<<<TT, 256, 0, stream>>>(actw0, actw1, cC, sel, abx);

  // partials[z] = abx @ Wdx^T slice z  (M=2048, N=2048, K=8704, split-K=4 -> 256 blocks, no atomics)
  gemm256<3><<<dim3(8, 8, 4), 512, 0, stream>>>(abx, Wdx, parts, KXD, KXD/4, HD);

  // out = sum of 4 partials
  reduce4_kernel<<<4096, 256, 0, stream>>>(parts, (float*)d_out);
}

// Round 12
// 434.646 us; speedup vs baseline: 1.0491x; 1.0045x over previous
//
#include <hip/hip_runtime.h>
#include <hip/hip_bf16.h>

typedef __attribute__((ext_vector_type(8))) short v8s;   // 8 x bf16 (as i16)
typedef __attribute__((ext_vector_type(4))) float v4f;
typedef unsigned short u16;

static constexpr int TT = 2048;        // tokens
static constexpr int HD = 2048;        // hidden
static constexpr int FD = 8192;        // ffn dim
static constexpr int NE = 8;           // experts
static constexpr int NR = 16;          // lora rank
static constexpr int NXE = 2*FD;       // 16384: merged [Wg | Wu] cols
static constexpr int CU_OFF = FD;      // up offset inside CGU row
static constexpr int KXD = FD + 512;   // 8704 = 136*64 ext K for down GEMM (34*64*4)

// ---------- helpers ----------
__device__ __forceinline__ u16 f2b(float f) {            // fp32 -> bf16 RNE
  union { float f; unsigned u; } v; v.f = f;
  unsigned r = v.u + 0x7FFFu + ((v.u >> 16) & 1u);
  return (u16)(r >> 16);
}
__device__ __forceinline__ float b2f(u16 h) {
  union { unsigned u; float f; } v; v.u = ((unsigned)h) << 16;
  return v.f;
}
__device__ __forceinline__ v8s pack8(v4f a, v4f b) {
  v8s r;
  r[0]=(short)f2b(a.x); r[1]=(short)f2b(a.y); r[2]=(short)f2b(a.z); r[3]=(short)f2b(a.w);
  r[4]=(short)f2b(b.x); r[5]=(short)f2b(b.y); r[6]=(short)f2b(b.z); r[7]=(short)f2b(b.w);
  return r;
}
__device__ __forceinline__ void gload_lds16(const void* g, void* l) {
  __builtin_amdgcn_global_load_lds(
      (const __attribute__((address_space(1))) unsigned int*)g,
      (__attribute__((address_space(3))) unsigned int*)l, 16, 0, 0);
}
__device__ __forceinline__ void barrier_pin() {
  __builtin_amdgcn_s_barrier();
  __builtin_amdgcn_sched_barrier(0);
}
__device__ __forceinline__ void vm_wait4() { asm volatile("s_waitcnt vmcnt(4)" ::: "memory"); }
__device__ __forceinline__ void vm_wait0() { asm volatile("s_waitcnt vmcnt(0)" ::: "memory"); }

template<int Q>
__device__ __forceinline__ void mmq(v4f (&acc)[8][4], const v8s (&af)[2][2], const v8s (&bf)[4][2]) {
  __builtin_amdgcn_s_setprio(1);
  #pragma unroll
  for (int m2 = 0; m2 < 2; ++m2)
    #pragma unroll
    for (int nf = 0; nf < 4; ++nf) {
      acc[Q*2+m2][nf] = __builtin_amdgcn_mfma_f32_16x16x32_bf16(af[m2][0], bf[nf][0], acc[Q*2+m2][nf], 0, 0, 0);
      acc[Q*2+m2][nf] = __builtin_amdgcn_mfma_f32_16x16x32_bf16(af[m2][1], bf[nf][1], acc[Q*2+m2][nf], 0, 0, 0);
    }
  __builtin_amdgcn_s_setprio(0);
}

// ---------- mega prep v5: one-shot (v2 shape), 16 fp32/thread, router fused, no NT ----------
// blocks (4096 elems each unless noted):
//  [0,1024) h->hb  [1024,5120) Wg  [5120,9216) Wu  [9216,13312) Wd->Wdx(ld)
//  [13312,13376) Ag  [13376,13440) Au  [13440,13696) Bg  [13696,13952) Bu
//  [13952,14208) Ad  [14208,14464) Bd->Wdx ext  [14464,14592) zero hAx
//  [14592,15104) router (4 tokens/block)
static constexpr int PREP_BLOCKS = 15104;
__global__ __launch_bounds__(256)
void prep_kernel(const float* __restrict__ h, const float* __restrict__ Wg,
                 const float* __restrict__ Wu, const float* __restrict__ Wd,
                 const float* __restrict__ Ag, const float* __restrict__ Au,
                 const float* __restrict__ Bg, const float* __restrict__ Bu,
                 const float* __restrict__ Ad, const float* __restrict__ Bd,
                 const float* __restrict__ gw,
                 u16* __restrict__ hb, u16* __restrict__ Bgux, u16* __restrict__ Agu,
                 u16* __restrict__ Wdx, u16* __restrict__ Bgb, u16* __restrict__ Bub,
                 u16* __restrict__ Adb, float* __restrict__ hAx,
                 int* __restrict__ sel, int* __restrict__ count,
                 int* __restrict__ listTok, float* __restrict__ listW) {
  const int b = blockIdx.x, tid = threadIdx.x;
  auto cast16 = [&](const float* s, u16* d, long blk) {
    long i = blk*4096 + (long)tid*16;
    v4f a0 = *(const v4f*)(s+i),    a1 = *(const v4f*)(s+i+4);
    v4f a2 = *(const v4f*)(s+i+8),  a3 = *(const v4f*)(s+i+12);
    *(v8s*)(d+i)   = pack8(a0, a1);
    *(v8s*)(d+i+8) = pack8(a2, a3);
  };
  if (b < 1024) { cast16(h, hb, b); }
  else if (b < 5120)  { cast16(Wg, Bgux, b-1024); }
  else if (b < 9216)  { cast16(Wu, Bgux + (size_t)FD*HD, b-5120); }
  else if (b < 13312) {
    long idx = (long)(b-9216)*4096 + (long)tid*16;   // over [HD][FD]
    long r = idx >> 13; int c = (int)(idx & 8191);
    const float* s = Wd + r*FD + c;
    u16* d = Wdx + r*KXD + c;
    v4f a0 = *(const v4f*)s,     a1 = *(const v4f*)(s+4);
    v4f a2 = *(const v4f*)(s+8), a3 = *(const v4f*)(s+12);
    *(v8s*)d     = pack8(a0, a1);
    *(v8s*)(d+8) = pack8(a2, a3);
  }
  else if (b < 13376) { cast16(Ag, Agu, b-13312); }
  else if (b < 13440) { cast16(Au, Agu + (size_t)128*HD, b-13376); }
  else if (b < 13696) { cast16(Bg, Bgb, b-13440); }
  else if (b < 13952) { cast16(Bu, Bub, b-13696); }
  else if (b < 14208) { cast16(Ad, Adb, b-13952); }
  else if (b < 14464) {
    long idx = (long)(b-14208)*4096 + (long)tid*16;  // over [HD][512] ext cols
    int hrow = (int)(idx >> 9); int c = (int)(idx & 511);
    u16* d = Wdx + (size_t)hrow*KXD + FD + c;
    if (c < 128) {            // one full (e, r0..15) row per 16-chunk
      const float* s = Bd + ((size_t)(c>>4)*HD + hrow)*16;
      v4f a0 = *(const v4f*)s,     a1 = *(const v4f*)(s+4);
      v4f a2 = *(const v4f*)(s+8), a3 = *(const v4f*)(s+12);
      *(v8s*)d     = pack8(a0, a1);
      *(v8s*)(d+8) = pack8(a2, a3);
    } else {
      v8s z = {0,0,0,0,0,0,0,0};
      *(v8s*)d = z; *(v8s*)(d+8) = z;
    }
  }
  else if (b < 14592) {
    long i = (long)(b-14464)*4096 + (long)tid*16;
    v4f z = {0.f,0.f,0.f,0.f};
    *(v4f*)(hAx+i) = z; *(v4f*)(hAx+i+4) = z;
    *(v4f*)(hAx+i+8) = z; *(v4f*)(hAx+i+12) = z;
  }
  else {   // router: one token per wave, 4 per block
    int t = (b - 14592)*4 + (tid >> 6);
    int lane = tid & 63;
    const float* hp = h + (size_t)t * HD;
    float acc[8] = {0,0,0,0,0,0,0,0};
    for (int i = lane; i < HD; i += 64) {
      float hv = hp[i];
      #pragma unroll
      for (int e = 0; e < 8; ++e) acc[e] += hv * gw[e*HD + i];
    }
    #pragma unroll
    for (int off = 32; off > 0; off >>= 1) {
      #pragma unroll
      for (int e = 0; e < 8; ++e) acc[e] += __shfl_xor(acc[e], off, 64);
    }
    if (lane == 0) {
      int e0 = -1, e1 = -1; float b0 = -1e30f, b1 = -1e30f;
      #pragma unroll
      for (int e = 0; e < 8; ++e) {
        float v = acc[e];
        if (v > b0) { b1 = b0; e1 = e0; b0 = v; e0 = e; }
        else if (v > b1) { b1 = v; e1 = e; }
      }
      float p1 = __expf(b1 - b0);            // p0 = 1
      float w0 = 1.f / (1.f + p1);
      float w1 = p1 * w0;
      sel[2*t] = e0; sel[2*t+1] = e1;
      int pos0 = atomicAdd(&count[e0], 1);
      listTok[e0*TT + pos0] = t;           listW[e0*TT + pos0] = w0;
      int pos1 = atomicAdd(&count[e1], 1);
      listTok[e1*TT + pos1] = t | (1<<20); listW[e1*TT + pos1] = w1;
    }
  }
}

// ---------- 128x128x64 bf16 GEMM (m97 structure), C = A @ B^T, split-K atomic ----------
__global__ __launch_bounds__(256)
void gemm128a(const u16* __restrict__ A, const u16* __restrict__ B, float* __restrict__ Cout,
              int K, int ldc) {
  __shared__ u16 As[128*64];
  __shared__ u16 Bs[128*64];
  const int tid  = threadIdx.x;
  const int lane = tid & 63, wid = tid >> 6;
  const int gx = gridDim.x;
  const int lin = blockIdx.y * gx + blockIdx.x;
  const int chunk = (gx * gridDim.y) >> 3;
  const int wg = (lin & 7) * chunk + (lin >> 3);
  const int m0 = (wg % gx) * 128, n0 = (wg / gx) * 128;
  const int kc = K / gridDim.z;
  const int kbeg = blockIdx.z * kc;
  const int wr = wid >> 1, wc = wid & 1;
  const int lrow = lane >> 3, lcol = (lane & 7) * 8;
  v4f acc[4][4];
  #pragma unroll
  for (int mi = 0; mi < 4; ++mi)
    #pragma unroll
    for (int ni = 0; ni < 4; ++ni) acc[mi][ni] = (v4f){0.f,0.f,0.f,0.f};

  for (int k0 = kbeg; k0 < kbeg + kc; k0 += 64) {
    #pragma unroll
    for (int it = 0; it < 4; ++it) {
      int seg = wid*4 + it;
      int row = seg*8 + lrow;
      gload_lds16(A + (size_t)(m0+row)*K + k0 + lcol, As + seg*512);
      gload_lds16(B + (size_t)(n0+row)*K + k0 + lcol, Bs + seg*512);
    }
    __syncthreads();
    #pragma unroll
    for (int kk = 0; kk < 64; kk += 32) {
      v8s af[4], bfr[4];
      #pragma unroll
      for (int mi = 0; mi < 4; ++mi)
        af[mi] = *(const v8s*)(As + (wr*64 + mi*16 + (lane&15))*64 + kk + (lane>>4)*8);
      #pragma unroll
      for (int ni = 0; ni < 4; ++ni)
        bfr[ni] = *(const v8s*)(Bs + (wc*64 + ni*16 + (lane&15))*64 + kk + (lane>>4)*8);
      #pragma unroll
      for (int mi = 0; mi < 4; ++mi)
        #pragma unroll
        for (int ni = 0; ni < 4; ++ni)
          acc[mi][ni] = __builtin_amdgcn_mfma_f32_16x16x32_bf16(af[mi], bfr[ni], acc[mi][ni], 0, 0, 0);
    }
    __syncthreads();
  }

  #pragma unroll
  for (int mi = 0; mi < 4; ++mi)
    #pragma unroll
    for (int j = 0; j < 4; ++j) {
      int row = m0 + wr*64 + mi*16 + (lane>>4)*4 + j;
      size_t base = (size_t)row*ldc + n0 + wc*64 + (lane&15);
      #pragma unroll
      for (int ni = 0; ni < 4; ++ni)
        atomicAdd(&Cout[base + ni*16], acc[mi][ni][j]);
    }
}

// ---------- 256x256 8-phase bf16 GEMM, C = A @ B^T  (T1+T2+T3+T4+T5) ----------
// MODE 0: bf16 store. MODE 3: fp32 per-z-slice partial store (no atomics).
template<int MODE>
__global__ __launch_bounds__(512, 2)
void gemm256(const u16* __restrict__ A, const u16* __restrict__ B, void* __restrict__ Cout,
             int ldk, int kchunk, int ldc) {
  __shared__ u16 lds[2][2][2][8192];
  const int tid = threadIdx.x, lane = tid & 63, wid = tid >> 6;
  const int gx = gridDim.x;
  const int nwg = gx * gridDim.y;
  const int lin = blockIdx.y * gx + blockIdx.x;
  const int chunk = nwg >> 3;                       // nwg % 8 == 0 by construction
  const int wg = (lin & 7) * chunk + (lin >> 3);    // bijective XCD swizzle
  const int m0 = (wg % gx) * 256, n0 = (wg / gx) * 256;
  const long kbeg = (long)blockIdx.z * kchunk;
  const int NK = kchunk >> 6, NI = NK >> 1;         // NK even
  const int wr = wid >> 2, wc = wid & 3;

  const int s_r = (wid << 4) + (lane >> 3);
  const int s_c = lane & 7;

  auto STAGE = [&](int slot, int ab, int half, const u16* M, int rc0, int kt) {
    const u16* g0 = M + (size_t)(rc0 + half*128 + s_r) * ldk + kbeg + kt*64 + ((s_c ^ (s_r & 7)) << 3);
    gload_lds16(g0, &lds[slot][ab][half][wid << 10]);
    const int r1 = s_r + 8;
    const u16* g1 = M + (size_t)(rc0 + half*128 + r1) * ldk + kbeg + kt*64 + ((s_c ^ (r1 & 7)) << 3);
    gload_lds16(g1, &lds[slot][ab][half][(wid << 10) + 512]);
  };
  auto LDA = [&](int slot, int mf, int c16b) -> v8s {
    int rr = (mf << 4) + (lane & 15);
    return *(const v8s*)&lds[slot][0][wr][rr*64 + (((c16b + (lane >> 4)) ^ (rr & 7)) << 3)];
  };
  auto LDB = [&](int slot, int nf, int c16b) -> v8s {
    int row = (wc << 6) + (nf << 4) + (lane & 15);
    int rr = row & 127;
    return *(const v8s*)&lds[slot][1][row >> 7][rr*64 + (((c16b + (lane >> 4)) ^ (rr & 7)) << 3)];
  };

  v4f acc[8][4];
  #pragma unroll
  for (int mf = 0; mf < 8; ++mf)
    #pragma unroll
    for (int nf = 0; nf < 4; ++nf) acc[mf][nf] = (v4f){0.f,0.f,0.f,0.f};

  STAGE(0,1,0,B,n0,0); STAGE(0,1,1,B,n0,0);
  STAGE(0,0,0,A,m0,0); STAGE(0,0,1,A,m0,0);
  STAGE(1,1,0,B,n0,1); STAGE(1,1,1,B,n0,1);
  vm_wait4();
  barrier_pin();

  for (int i = 0; i < NI; ++i) {
    const int kt0 = 2*i, kt1 = kt0 + 1;
    const int kt2c = (kt0 + 2 < NK) ? kt0 + 2 : kt0;
    const bool s45 = (kt0 + 2 < NK), s67 = (kt1 + 2 < NK);
    v8s bf[4][2], af[2][2];
    // ---- phase 0 (slot0, q0)
    #pragma unroll
    for (int nf = 0; nf < 4; ++nf) { bf[nf][0] = LDB(0,nf,0); bf[nf][1] = LDB(0,nf,4); }
    af[0][0]=LDA(0,0,0); af[0][1]=LDA(0,0,4); af[1][0]=LDA(0,1,0); af[1][1]=LDA(0,1,4);
    STAGE(1,0,0,A,m0,kt1);
    barrier_pin(); mmq<0>(acc,af,bf); barrier_pin();
    // ---- phase 1 (slot0, q1)
    af[0][0]=LDA(0,2,0); af[0][1]=LDA(0,2,4); af[1][0]=LDA(0,3,0); af[1][1]=LDA(0,3,4);
    STAGE(1,0,1,A,m0,kt1);
    barrier_pin(); mmq<1>(acc,af,bf); barrier_pin();
    // ---- phase 2 (slot0, q2)
    af[0][0]=LDA(0,4,0); af[0][1]=LDA(0,4,4); af[1][0]=LDA(0,5,0); af[1][1]=LDA(0,5,4);
    STAGE(0,1,0,B,n0,kt2c);
    barrier_pin(); mmq<2>(acc,af,bf); barrier_pin();
    // ---- phase 3 (slot0, q3)
    af[0][0]=LDA(0,6,0); af[0][1]=LDA(0,6,4); af[1][0]=LDA(0,7,0); af[1][1]=LDA(0,7,4);
    STAGE(0,1,1,B,n0,kt2c);
    vm_wait4();
    barrier_pin(); mmq<3>(acc,af,bf); barrier_pin();
    // ---- phase 4 (slot1, q0)
    #pragma unroll
    for (int nf = 0; nf < 4; ++nf) { bf[nf][0] = LDB(1,nf,0); bf[nf][1] = LDB(1,nf,4); }
    af[0][0]=LDA(1,0,0); af[0][1]=LDA(1,0,4); af[1][0]=LDA(1,1,0); af[1][1]=LDA(1,1,4);
    if (s45) STAGE(0,0,0,A,m0,kt0+2);
    barrier_pin(); mmq<0>(acc,af,bf); barrier_pin();
    // ---- phase 5 (slot1, q1)
    af[0][0]=LDA(1,2,0); af[0][1]=LDA(1,2,4); af[1][0]=LDA(1,3,0); af[1][1]=LDA(1,3,4);
    if (s45) STAGE(0,0,1,A,m0,kt0+2);
    barrier_pin(); mmq<1>(acc,af,bf); barrier_pin();
    // ---- phase 6 (slot1, q2)
    af[0][0]=LDA(1,4,0); af[0][1]=LDA(1,4,4); af[1][0]=LDA(1,5,0); af[1][1]=LDA(1,5,4);
    if (s67) STAGE(1,1,0,B,n0,kt1+2);
    barrier_pin(); mmq<2>(acc,af,bf); barrier_pin();
    // ---- phase 7 (slot1, q3)
    af[0][0]=LDA(1,6,0); af[0][1]=LDA(1,6,4); af[1][0]=LDA(1,7,0); af[1][1]=LDA(1,7,4);
    if (s67) STAGE(1,1,1,B,n0,kt1+2);
    vm_wait4();
    barrier_pin(); mmq<3>(acc,af,bf); barrier_pin();
  }
  vm_wait0();

  if (MODE == 0) {
    u16* C = (u16*)Cout;
    #pragma unroll
    for (int mf = 0; mf < 8; ++mf)
      #pragma unroll
      for (int j = 0; j < 4; ++j) {
        int row = m0 + wr*128 + mf*16 + (lane>>4)*4 + j;
        size_t base = (size_t)row*ldc + n0 + wc*64 + (lane&15);
        #pragma unroll
        for (int nf = 0; nf < 4; ++nf)
          C[base + nf*16] = f2b(acc[mf][nf][j]);
      }
  } else {
    float* C = (float*)Cout + (size_t)blockIdx.z * TT * HD;   // per-slice partial
    #pragma unroll
    for (int mf = 0; mf < 8; ++mf)
      #pragma unroll
      for (int j = 0; j < 4; ++j) {
        int row = m0 + wr*128 + mf*16 + (lane>>4)*4 + j;
        size_t base = (size_t)row*ldc + n0 + wc*64 + (lane&15);
        #pragma unroll
        for (int nf = 0; nf < 4; ++nf)
          C[base + nf*16] = acc[mf][nf][j];
      }
  }
}

// ---------- reduce: out = sum of 4 fp32 partials ----------
__global__ __launch_bounds__(256)
void reduce4_kernel(const float* __restrict__ P, float* __restrict__ out) {
  long i = ((long)blockIdx.x * 256 + threadIdx.x) * 4;
  const size_t S = (size_t)TT * HD;
  v4f s = *(const v4f*)(P + i);
  s = s + *(const v4f*)(P + S + i);
  s = s + *(const v4f*)(P + 2*S + i);
  s = s + *(const v4f*)(P + 3*S + i);
  *(v4f*)(out + i) = s;
}

// ---------- expert kernel v3: register double-buffer for ALL MFMA operands ----------
// grid (128 groups, NE, 8 f-blocks). Per block: 16 tokens x 1024 f-cols.
static constexpr int HA_LD = 40;
static constexpr int AW_LD = 72;
static constexpr int CT_LD = 72;

struct PF {      // per-chunk prefetch state
  v8s bg[4], bu[4], ad[2];
  v8s rg0, ru0, rg1, ru1;
};

__global__ __launch_bounds__(256)
void expert_kernel(const u16* __restrict__ CGU,                                // [TT][NXE]
                   const float* __restrict__ hAx,                              // [TT][256] fp32
                   const u16* __restrict__ Bgb, const u16* __restrict__ Bub,   // [E][F][16] bf16
                   const u16* __restrict__ Adb,                                // [E][16][F] bf16
                   const int* __restrict__ count, const int* __restrict__ listTok,
                   const float* __restrict__ listW,
                   u16* __restrict__ actw0, u16* __restrict__ actw1,           // [TT+1][F]
                   float* __restrict__ cC) {                                   // [TT+1][2][16]
  const int e = blockIdx.y, g = blockIdx.x, fb = blockIdx.z;
  const int n = count[e];
  if (g*16 >= n) return;
  const int tid = threadIdx.x, lane = tid & 63, w = tid >> 6;
  __shared__ u16 hAg[16*HA_LD], hAu[16*HA_LD];
  __shared__ u16 AWs[4][16*AW_LD];
  __shared__ u16 cgT[4][16*CT_LD], cuT[4][16*CT_LD];
  __shared__ int sTok[16], sSlot[16];
  __shared__ float sW[16];
  __shared__ float dAred[4][256];

  if (tid < 16) {
    int idx = g*16 + tid;
    if (idx < n) {
      int ent = listTok[e*TT + idx];
      sTok[tid] = ent & 0xFFFF; sSlot[tid] = (ent >> 20) & 1; sW[tid] = listW[e*TT + idx];
    } else { sTok[tid] = TT; sSlot[tid] = 0; sW[tid] = 0.f; }
  }
  __syncthreads();
  if (tid < 128) {   // stage hA (both tensors) from hAx fp32, zero-pad K 16..31
    int tensor = tid >> 6;
    int sub = tid & 63;
    int row = sub >> 2, c8 = (sub & 3) * 8;
    int trd = min(sTok[row], TT - 1);
    u16 vals[8];
    if (c8 < 16) {
      const float* src = hAx + (size_t)trd*256 + tensor*128 + e*NR + c8;
      v4f a = *(const v4f*)src, b = *(const v4f*)(src + 4);
      v8s p = pack8(a, b);
      #pragma unroll
      for (int q = 0; q < 8; ++q) vals[q] = (u16)p[q];
    } else {
      #pragma unroll
      for (int q = 0; q < 8; ++q) vals[q] = 0;
    }
    u16* dst = (tensor ? hAu : hAg) + row*HA_LD + c8;
    #pragma unroll
    for (int q = 0; q < 8; ++q) dst[q] = vals[q];
  }
  __syncthreads();

  int tR[4], slR[4]; float wR[4];
  #pragma unroll
  for (int j = 0; j < 4; ++j) {
    int r = (lane>>4)*4 + j;
    tR[j] = sTok[r]; slR[j] = sSlot[r]; wR[j] = sW[r];
  }
  const int khalf = lane >> 4;
  v8s afg = *(const v8s*)(hAg + (lane&15)*HA_LD + khalf*8);
  v8s afu = *(const v8s*)(hAu + (lane&15)*HA_LD + khalf*8);
  v4f accDA = (v4f){0.f,0.f,0.f,0.f};
  u16* aww = AWs[w]; u16* cgw = cgT[w]; u16* cuw = cuT[w];
  const v8s zero8 = {0,0,0,0,0,0,0,0};
  const u16* BgE = Bgb + (size_t)e*FD*16;
  const u16* BuE = Bub + (size_t)e*FD*16;
  const u16* AdE = Adb + (size_t)e*16*FD;

  const int srj = lane >> 2, sc = (lane & 3) * 16;
  const int srow = lane >> 3, c8s = (lane & 7) * 8;
  const size_t trdA = (size_t)min(sTok[srow], TT - 1);
  const size_t trdB = (size_t)min(sTok[srow + 8], TT - 1);

  auto LOADPF = [&](int ch, PF& p) {
    const int f0 = ch * 64;
    #pragma unroll
    for (int nf = 0; nf < 4; ++nf) {
      int f = f0 + nf*16 + (lane & 15);
      p.bg[nf] = (khalf < 2) ? *(const v8s*)(BgE + (size_t)f*16 + khalf*8) : zero8;
      p.bu[nf] = (khalf < 2) ? *(const v8s*)(BuE + (size_t)f*16 + khalf*8) : zero8;
    }
    #pragma unroll
    for (int ks = 0; ks < 2; ++ks)
      p.ad[ks] = *(const v8s*)(AdE + (size_t)(lane&15)*FD + f0 + ks*32 + khalf*8);
    p.rg0 = *(const v8s*)(CGU + trdA*NXE + f0 + c8s);
    p.ru0 = *(const v8s*)(CGU + trdA*NXE + CU_OFF + f0 + c8s);
    p.rg1 = *(const v8s*)(CGU + trdB*NXE + f0 + c8s);
    p.ru1 = *(const v8s*)(CGU + trdB*NXE + CU_OFF + f0 + c8s);
  };

  auto COMPUTE = [&](int ch, const PF& p) {
    const int f0 = ch * 64;
    *(v8s*)(cgw + srow*CT_LD + c8s)     = p.rg0;
    *(v8s*)(cgw + (srow+8)*CT_LD + c8s) = p.rg1;
    *(v8s*)(cuw + srow*CT_LD + c8s)     = p.ru0;
    *(v8s*)(cuw + (srow+8)*CT_LD + c8s) = p.ru1;
    v4f dg[4], du[4];
    #pragma unroll
    for (int nf = 0; nf < 4; ++nf) {
      dg[nf] = __builtin_amdgcn_mfma_f32_16x16x32_bf16(afg, p.bg[nf], (v4f){0.f,0.f,0.f,0.f}, 0, 0, 0);
      du[nf] = __builtin_amdgcn_mfma_f32_16x16x32_bf16(afu, p.bu[nf], (v4f){0.f,0.f,0.f,0.f}, 0, 0, 0);
    }
    #pragma unroll
    for (int nf = 0; nf < 4; ++nf) {
      #pragma unroll
      for (int j = 0; j < 4; ++j) {
        int rj = (lane>>4)*4 + j;
        int fi = nf*16 + (lane&15);
        float cgv = b2f(cgw[rj*CT_LD + fi]);
        float cuv = b2f(cuw[rj*CT_LD + fi]);
        float gv = cgv + 2.f * dg[nf][j];
        float uv = cuv + 2.f * du[nf][j];
        float a  = gv * __builtin_amdgcn_rcpf(1.f + __expf(-gv)) * uv;   // silu(g)*u
        aww[rj*AW_LD + fi] = f2b(wR[j] * a);
      }
    }
    {
      int st = sTok[srj], ss = sSlot[srj];
      u16* dst = (ss ? actw1 : actw0) + (size_t)st*FD + f0 + sc;
      *(v8s*)dst       = *(const v8s*)(aww + srj*AW_LD + sc);
      *(v8s*)(dst + 8) = *(const v8s*)(aww + srj*AW_LD + sc + 8);
    }
    #pragma unroll
    for (int ks = 0; ks < 2; ++ks) {
      v8s aA = *(const v8s*)(aww + (lane&15)*AW_LD + ks*32 + khalf*8);
      accDA = __builtin_amdgcn_mfma_f32_16x16x32_bf16(aA, p.ad[ks], accDA, 0, 0, 0);
    }
  };

  const int ch0 = fb*16 + w;
  PF pA, pB;
  LOADPF(ch0,      pA);
  LOADPF(ch0 + 4,  pB);
  COMPUTE(ch0,     pA);
  LOADPF(ch0 + 8,  pA);
  COMPUTE(ch0 + 4, pB);
  LOADPF(ch0 + 12, pB);
  COMPUTE(ch0 + 8, pA);
  COMPUTE(ch0 + 12, pB);

  #pragma unroll
  for (int j = 0; j < 4; ++j)
    dAred[w][((lane>>4)*4 + j)*16 + (lane&15)] = accDA[j];
  __syncthreads();
  {
    int row = tid >> 4, col = tid & 15;
    float s2 = dAred[0][row*16+col] + dAred[1][row*16+col] + dAred[2][row*16+col] + dAred[3][row*16+col];
    atomicAdd(&cC[((size_t)sTok[row]*2 + sSlot[row])*16 + col], 2.f * s2);
  }
}

// ---------- combine: abx[t] = [actw0+actw1 (bf16), scattered c coefs, zeros] ----------
__global__ __launch_bounds__(256)
void combine2_kernel(const u16* __restrict__ a0, const u16* __restrict__ a1,
                     const float* __restrict__ cC, const int* __restrict__ sel,
                     u16* __restrict__ abx) {
  int t = blockIdx.x, tid = threadIdx.x;
  const u16* p0 = a0 + (size_t)t * FD;
  const u16* p1 = a1 + (size_t)t * FD;
  u16* po = abx + (size_t)t * KXD;
  for (int i = tid * 8; i < FD; i += 256 * 8) {
    v8s x = *(const v8s*)(p0 + i);
    v8s y = *(const v8s*)(p1 + i);
    v8s o;
    #pragma unroll
    for (int j = 0; j < 8; ++j) o[j] = (short)f2b(b2f((u16)x[j]) + b2f((u16)y[j]));
    *(v8s*)(po + i) = o;
  }
  for (int c = tid; c < 512; c += 256) {  // ext cols; c>=128 zeroed
    float v = 0.f;
    if (c < 128) {
      int e_i = c >> 4, r = c & 15;
      if (sel[2*t]     == e_i) v += cC[((size_t)t*2 + 0)*16 + r];
      if (sel[2*t + 1] == e_i) v += cC[((size_t)t*2 + 1)*16 + r];
    }
    po[FD + c] = f2b(v);
  }
}

// ---------- launch ----------
extern "C" void kernel_launch(void* const* d_in, const int* in_sizes, int n_in,
                              void* d_out, int out_size, void* d_ws, size_t ws_size,
                              hipStream_t stream) {
  (void)in_sizes; (void)n_in; (void)out_size; (void)ws_size;
  const float* h  = (const float*)d_in[0];
  const float* gw = (const float*)d_in[1];
  const float* Wg = (const float*)d_in[2];
  const float* Wu = (const float*)d_in[3];
  const float* Wd = (const float*)d_in[4];
  const float* Ag = (const float*)d_in[5];
  const float* Bg = (const float*)d_in[6];
  const float* Au = (const float*)d_in[7];
  const float* Bu = (const float*)d_in[8];
  const float* Ad = (const float*)d_in[9];
  const float* Bd = (const float*)d_in[10];

  char* ws = (char*)d_ws;
  size_t off = 0;
  auto alloc = [&](size_t bytes) { size_t c = off; off += (bytes + 255) & ~(size_t)255; return c; };
  u16*  hb     = (u16*)(ws + alloc((size_t)TT*HD*2));             // 8 MB
  u16*  Bgux   = (u16*)(ws + alloc((size_t)(TT+1)*FD*2*2));       // 67.2 MB [Wg|Wu]; actw0/1; down partials
  u16*  Agu    = (u16*)(ws + alloc((size_t)256*HD*2));            // 1 MB [Ag all|Au all]
  u16*  Wdx    = (u16*)(ws + alloc((size_t)HD*KXD*2));            // 35.7 MB [HD][KXD]
  u16*  CGU    = (u16*)(ws + alloc((size_t)TT*NXE*2));            // 64 MB [TT][NXE]; later abx [TT][KXD]
  u16*  Bgb    = (u16*)(ws + alloc((size_t)NE*FD*16*2));          // 2 MB bf16
  u16*  Bub    = (u16*)(ws + alloc((size_t)NE*FD*16*2));          // 2 MB
  u16*  Adb    = (u16*)(ws + alloc((size_t)NE*16*FD*2));          // 2 MB
  float* hAx   = (float*)(ws + alloc((size_t)TT*256*4));          // 2 MB
  size_t cC_bytes = ((size_t)(TT+1)*2*16*4 + 255) & ~(size_t)255;
  float* cC    = (float*)(ws + alloc((size_t)(TT+1)*2*16*4));     // adjacent to count
  int*  count  = (int*)(ws + alloc(256));
  int*  sel    = (int*)(ws + alloc((size_t)TT*2*4));
  int*  listTok= (int*)(ws + alloc((size_t)NE*TT*4));
  float* listW = (float*)(ws + alloc((size_t)NE*TT*4));
  u16*  actw0  = Bgux;                                  // alias: Bgux dead after gate/up GEMM
  u16*  actw1  = Bgux + (size_t)(TT+1)*FD;
  u16*  abx    = CGU;                                   // alias: CGU dead after expert_kernel
  float* parts = (float*)Bgux;                          // alias: actw dead after combine2 (64 MB <= 67.2)

  // single memset: cC (fp32 zeros) + count (adjacent)
  hipMemsetAsync(cC, 0, cC_bytes + 256, stream);

  // mega-prep: all casts + Bd-ext + hAx zero + router (one-shot blocks)
  prep_kernel<<<PREP_BLOCKS, 256, 0, stream>>>(h, Wg, Wu, Wd, Ag, Au, Bg, Bu, Ad, Bd, gw,
                                               hb, Bgux, Agu, Wdx, Bgb, Bub, Adb, hAx,
                                               sel, count, listTok, listW);

  // hAx = h @ [Ag;Au]^T  (M=2048, N=256, K=2048, split-K=8 -> 256 blocks)
  gemm128a<<<dim3(16, 2, 8), 256, 0, stream>>>(hb, Agu, hAx, HD, 256);

  // CGU = h @ [Wg|Wu]^T  (M=2048, N=16384, K=2048) -> 512 blocks = 2 exact rounds
  gemm256<0><<<dim3(8, 64, 1), 512, 0, stream>>>(hb, Bgux, CGU, HD, HD, NXE);

  // per-expert: deltas, act, weighted act into slot buffers (aliasing Bgux), c coefs
  expert_kernel<<<dim3(128, NE, 8), 256, 0, stream>>>(CGU, hAx, Bgb, Bub, Adb, count, listTok, listW,
                                                      actw0, actw1, cC);

  // abx = [actw0+actw1, c-scatter, zeros]  (writes into the dead CGU region)
  combine2_kernel<<<TT, 256, 0, stream>>>(actw0, actw1, cC, sel, abx);

  // partials[z] = abx @ Wdx^T slice z  (M=2048, N=2048, K=8704, split-K=4 -> 256 blocks, no atomics)
  gemm256<3><<<dim3(8, 8, 4), 512, 0, stream>>>(abx, Wdx, parts, KXD, KXD/4, HD);

  // out = sum of 4 partials
  reduce4_kernel<<<4096, 256, 0, stream>>>(parts, (float*)d_out);
}